// Round 6
// baseline (145.791 us; speedup 1.0000x reference)
//
#include <hip/hip_runtime.h>
#include <math.h>

#define N 4096
#define D 512
#define KPOS 5
#define KNEG 10

typedef short s16x8 __attribute__((ext_vector_type(8)));
typedef float f32x4 __attribute__((ext_vector_type(4)));

__device__ __forceinline__ unsigned short f2bf(float x) {
    unsigned u = __float_as_uint(x);
    unsigned r = (u + 0x7FFFu + ((u >> 16) & 1u)) >> 16;   // RNE
    return (unsigned short)r;
}
__device__ __forceinline__ float bf2f(unsigned short b) {
    return __uint_as_float(((unsigned)b) << 16);
}
__device__ __forceinline__ unsigned umax_(unsigned a, unsigned b) { return a > b ? a : b; }
__device__ __forceinline__ unsigned umin_(unsigned a, unsigned b) { return a < b ? a : b; }

// ---------------------------------------------------------------------------
// Kernel 1: normalize. anchor rows (eps 1e-8) -> bf16 hi/lo split (Ahi, Alo).
// sample rows (eps 1e-12) -> fp32 s_norm (for the loss kernel).
// ---------------------------------------------------------------------------
__global__ __launch_bounds__(256) void norm_kernel(const float* __restrict__ anchor,
                                                   const float* __restrict__ sample,
                                                   unsigned short* __restrict__ Ahi,
                                                   unsigned short* __restrict__ Alo,
                                                   float* __restrict__ s_norm) {
    const int wave = threadIdx.x >> 6, lane = threadIdx.x & 63;
    const int row = blockIdx.x * 4 + wave;
    const bool is_anchor = row < N;
    const float* in = is_anchor ? anchor + (size_t)row * D
                                : sample + (size_t)(row - N) * D;
    const float eps = is_anchor ? 1e-8f : 1e-12f;

    float v[8];
    float ss = 0.f;
#pragma unroll
    for (int e = 0; e < 8; ++e) {
        v[e] = in[lane + 64 * e];
        ss = fmaf(v[e], v[e], ss);
    }
#pragma unroll
    for (int off = 32; off > 0; off >>= 1) ss += __shfl_xor(ss, off);
    const float denom = fmaxf(sqrtf(ss), eps);

    if (is_anchor) {
        unsigned short* hi = Ahi + (size_t)row * D;
        unsigned short* lo = Alo + (size_t)row * D;
#pragma unroll
        for (int e = 0; e < 8; ++e) {
            const float x = v[e] / denom;
            const unsigned short h = f2bf(x);
            hi[lane + 64 * e] = h;
            lo[lane + 64 * e] = f2bf(x - bf2f(h));
        }
    } else {
        float* out = s_norm + (size_t)(row - N) * D;
#pragma unroll
        for (int e = 0; e < 8; ++e) out[lane + 64 * e] = v[e] / denom;
    }
}

// ---------------------------------------------------------------------------
// Kernel 2: sim = hi@hi^T + hi@lo^T + lo@hi^T (bf16 MFMA, eff. K = 1536).
// SYMMETRIC: the approximation is exactly symmetric (lo@lo^T dropped is
// symmetric), so only blocks with bi <= bj are computed; off-diagonal blocks
// are written twice (normal + transposed float4 mirror). Lower blocks exit.
// 128x128 tile, BK=64, 4 waves, 16x16x32 MFMA, double-buffered LDS with
// prefetch-before-compute, T2 XOR swizzle on the global source (rule #21).
// ---------------------------------------------------------------------------
#define TILE (128 * 64)

__device__ __forceinline__ void stage_tile(const unsigned short* __restrict__ sA,
                                           const unsigned short* __restrict__ sB,
                                           unsigned short* As, unsigned short* Bs,
                                           int rowA, int rowB, int kl, int t) {
#pragma unroll
    for (int i = 0; i < 4; ++i) {
        const int c = i * 256 + t;                 // 16B chunk id 0..1023
        const int r = c >> 3;                      // tile row 0..127
        const int ke = ((c & 7) ^ (r & 7)) * 8;    // swizzled k-element offset
        __builtin_amdgcn_global_load_lds(
            (const __attribute__((address_space(1))) void*)(sA + (size_t)(rowA + r) * D + kl + ke),
            (__attribute__((address_space(3))) void*)(As + c * 8), 16, 0, 0);
    }
#pragma unroll
    for (int i = 0; i < 4; ++i) {
        const int c = i * 256 + t;
        const int r = c >> 3;
        const int ke = ((c & 7) ^ (r & 7)) * 8;
        __builtin_amdgcn_global_load_lds(
            (const __attribute__((address_space(1))) void*)(sB + (size_t)(rowB + r) * D + kl + ke),
            (__attribute__((address_space(3))) void*)(Bs + c * 8), 16, 0, 0);
    }
}

__global__ __launch_bounds__(256) void gemm_bf16(const unsigned short* __restrict__ Ahi,
                                                 const unsigned short* __restrict__ Alo,
                                                 float* __restrict__ C) {
    const int bi = blockIdx.y, bj = blockIdx.x;
    if (bj < bi) return;                          // symmetry: upper triangle only

    __shared__ __align__(16) unsigned short As[2 * TILE];   // 2 x 16 KiB
    __shared__ __align__(16) unsigned short Bs[2 * TILE];

    const int t = threadIdx.x;
    const int l = t & 63;
    const int w = t >> 6;
    const int wr = w >> 1, wc = w & 1;
    const int rowA = bi * 128;
    const int rowB = bj * 128;
    const int lrow = l & 15, lgrp = l >> 4;

    f32x4 acc[4][4];
#pragma unroll
    for (int m = 0; m < 4; ++m)
#pragma unroll
        for (int n = 0; n < 4; ++n) acc[m][n] = (f32x4){0.f, 0.f, 0.f, 0.f};

    // prologue: stage tile 0 (phase 0 = hi*hi, kl = 0)
    stage_tile(Ahi, Ahi, As, Bs, rowA, rowB, 0, t);
    __syncthreads();

    for (int kc = 0; kc < 24; ++kc) {
        const int cur = kc & 1;
        if (kc < 23) {
            const int kn = kc + 1;
            const int phase = kn >> 3;             // 0: hi*hi, 1: hi*lo, 2: lo*hi
            const int kl = (kn & 7) * 64;
            stage_tile(phase == 2 ? Alo : Ahi, phase == 1 ? Alo : Ahi,
                       As + (cur ^ 1) * TILE, Bs + (cur ^ 1) * TILE,
                       rowA, rowB, kl, t);
        }

        const char* AsB = (const char*)(As + cur * TILE);
        const char* BsB = (const char*)(Bs + cur * TILE);
#pragma unroll
        for (int kk = 0; kk < 2; ++kk) {
            s16x8 af[4], bfr[4];
#pragma unroll
            for (int m = 0; m < 4; ++m) {
                const int row = wr * 64 + m * 16 + lrow;
                af[m] = *(const s16x8*)(AsB + row * 128 + (((kk * 4 + lgrp) ^ (row & 7)) * 16));
            }
#pragma unroll
            for (int n = 0; n < 4; ++n) {
                const int row = wc * 64 + n * 16 + lrow;
                bfr[n] = *(const s16x8*)(BsB + row * 128 + (((kk * 4 + lgrp) ^ (row & 7)) * 16));
            }
#pragma unroll
            for (int m = 0; m < 4; ++m)
#pragma unroll
                for (int n = 0; n < 4; ++n)
                    acc[m][n] = __builtin_amdgcn_mfma_f32_16x16x32_bf16(af[m], bfr[n], acc[m][n], 0, 0, 0);
        }
        __syncthreads();
    }

    // C/D layout: col = lane&15, row = (lane>>4)*4 + j
#pragma unroll
    for (int m = 0; m < 4; ++m) {
#pragma unroll
        for (int n = 0; n < 4; ++n) {
            const int col = rowB + wc * 64 + n * 16 + lrow;
            const int row0 = rowA + wr * 64 + m * 16 + lgrp * 4;
#pragma unroll
            for (int j = 0; j < 4; ++j)
                C[(size_t)(row0 + j) * N + col] = acc[m][n][j];
        }
    }
    if (bi != bj) {
        // mirror block: C[col][row0..row0+3] = acc[m][n] (contiguous float4)
#pragma unroll
        for (int m = 0; m < 4; ++m) {
#pragma unroll
            for (int n = 0; n < 4; ++n) {
                const int col = rowB + wc * 64 + n * 16 + lrow;
                const int row0 = rowA + wr * 64 + m * 16 + lgrp * 4;
                *(f32x4*)&C[(size_t)col * N + row0] = acc[m][n];
            }
        }
    }
}

// ---------------------------------------------------------------------------
// Kernel 3: wave-per-row top-5 / bottom-10, branchless on packed u32 keys.
// key = (monotone_fp32_bits & 0xFFFFF000) | idx12 (idx complemented for top
// so equal truncated values resolve to the LOWER index = jax stable order).
// ---------------------------------------------------------------------------
__global__ __launch_bounds__(256) void topk_kernel(const float* __restrict__ sim,
                                                   int* __restrict__ pos_idx,
                                                   int* __restrict__ neg_idx) {
    const int w = threadIdx.x >> 6, l = threadIdx.x & 63;
    const int row = blockIdx.x * 4 + w;
    const float* s = sim + (size_t)row * N;

    unsigned tk[KPOS], bk[KNEG];
#pragma unroll
    for (int q = 0; q < KPOS; ++q) tk[q] = 0u;
#pragma unroll
    for (int q = 0; q < KNEG; ++q) bk[q] = 0xFFFFFFFFu;

    for (int e = 0; e < 16; ++e) {
        const int base = 4 * (l + 64 * e);
        const float4 v4 = *(const float4*)&s[base];
        const float vv[4] = {v4.x, v4.y, v4.z, v4.w};
#pragma unroll
        for (int j = 0; j < 4; ++j) {
            unsigned u = __float_as_uint(vv[j]);
            u ^= ((unsigned)((int)u >> 31)) | 0x80000000u;   // monotone map
            const unsigned kv = u & 0xFFFFF000u;
            const int idx = base + j;

            unsigned c = kv | (unsigned)(4095 - idx);        // top key
#pragma unroll
            for (int q = 0; q < KPOS - 1; ++q) {
                const unsigned x = umax_(tk[q], c);
                c = umin_(tk[q], c);
                tk[q] = x;
            }
            tk[KPOS - 1] = umax_(tk[KPOS - 1], c);

            c = kv | (unsigned)idx;                          // bot key
#pragma unroll
            for (int q = 0; q < KNEG - 1; ++q) {
                const unsigned x = umin_(bk[q], c);
                c = umax_(bk[q], c);
                bk[q] = x;
            }
            bk[KNEG - 1] = umax_(bk[KNEG - 1], c);
        }
    }

    // ---- merge top-5 across the wave ----
    for (int it = 0; it < KPOS; ++it) {
        unsigned m = tk[0];
#pragma unroll
        for (int off = 32; off > 0; off >>= 1) m = umax_(m, (unsigned)__shfl_xor((int)m, off));
        if (l == 0) pos_idx[row * KPOS + it] = 4095 - (int)(m & 0xFFFu);
        if (tk[0] == m) {   // unique key -> exactly one lane pops
#pragma unroll
            for (int q = 0; q < KPOS - 1; ++q) tk[q] = tk[q + 1];
            tk[KPOS - 1] = 0u;
        }
    }

    // ---- merge bottom-10 across the wave ----
    for (int it = 0; it < KNEG; ++it) {
        unsigned m = bk[0];
#pragma unroll
        for (int off = 32; off > 0; off >>= 1) m = umin_(m, (unsigned)__shfl_xor((int)m, off));
        if (l == 0) neg_idx[row * KNEG + it] = (int)(m & 0xFFFu);
        if (bk[0] == m) {
#pragma unroll
            for (int q = 0; q < KNEG - 1; ++q) bk[q] = bk[q + 1];
            bk[KNEG - 1] = 0xFFFFFFFFu;
        }
    }
}

// ---------------------------------------------------------------------------
// Kernel 4: InfoNCE loss. 320 blocks x 4 waves x 16 rows; one atomic/block.
// ---------------------------------------------------------------------------
#define LOSS_BLOCKS 320
#define ROWS_PER_WAVE 16

__global__ __launch_bounds__(256) void loss_kernel(const float* __restrict__ s_norm,
                                                   const int* __restrict__ pos_idx,
                                                   const int* __restrict__ neg_idx,
                                                   float* __restrict__ out) {
    __shared__ float wsum[4];
    const int wave = threadIdx.x >> 6, lane = threadIdx.x & 63;
    const int gwave = blockIdx.x * 4 + wave;

    float lsum = 0.f;
    for (int rr = 0; rr < ROWS_PER_WAVE; ++rr) {
        const int j = gwave * ROWS_PER_WAVE + rr;
        const int ia = j / 5;
        const int p = j - ia * 5;
        const int iq = j & (N - 1);

        const float* q = s_norm + (size_t)iq * D;
        float qv[8];
#pragma unroll
        for (int e = 0; e < 8; ++e) qv[e] = q[lane + 64 * e];

        const int pi = pos_idx[ia * KPOS + p];
        const float* pv = s_norm + (size_t)pi * D;
        float accp = 0.f;
#pragma unroll
        for (int e = 0; e < 8; ++e) accp = fmaf(qv[e], pv[lane + 64 * e], accp);

        float accn[KNEG];
#pragma unroll
        for (int k = 0; k < KNEG; ++k) {
            const float* nv = s_norm + (size_t)neg_idx[ia * KNEG + k] * D;
            float a = 0.f;
#pragma unroll
            for (int e = 0; e < 8; ++e) a = fmaf(qv[e], nv[lane + 64 * e], a);
            accn[k] = a;
        }

#pragma unroll
        for (int off = 32; off > 0; off >>= 1) {
            accp += __shfl_xor(accp, off);
#pragma unroll
            for (int k = 0; k < KNEG; ++k) accn[k] += __shfl_xor(accn[k], off);
        }

        const float l0 = accp * 10.f;
        float m = l0;
#pragma unroll
        for (int k = 0; k < KNEG; ++k) m = fmaxf(m, accn[k] * 10.f);
        float ssum = expf(l0 - m);
#pragma unroll
        for (int k = 0; k < KNEG; ++k) ssum += expf(accn[k] * 10.f - m);
        lsum += logf(ssum) + m - l0;
    }

    if (lane == 0) wsum[wave] = lsum;
    __syncthreads();
    if (threadIdx.x == 0) {
        const float total = wsum[0] + wsum[1] + wsum[2] + wsum[3];
        atomicAdd(out, total * (1.0f / (float)(N * KPOS)));
    }
}

// ---------------------------------------------------------------------------
extern "C" void kernel_launch(void* const* d_in, const int* in_sizes, int n_in,
                              void* d_out, int out_size, void* d_ws, size_t ws_size,
                              hipStream_t stream) {
    const float* anchor = (const float*)d_in[0];
    const float* sample = (const float*)d_in[1];
    float* out = (float*)d_out;

    char* ws = (char*)d_ws;
    unsigned short* Ahi = (unsigned short*)ws;                              // 4 MiB
    unsigned short* Alo = (unsigned short*)(ws + (size_t)4 * 1024 * 1024);  // 4 MiB
    float* s_norm = (float*)(ws + (size_t)8 * 1024 * 1024);                 // 8 MiB
    float* sim    = (float*)(ws + (size_t)16 * 1024 * 1024);                // 64 MiB
    int* pos_idx  = (int*)(ws + (size_t)80 * 1024 * 1024);
    int* neg_idx  = (int*)(ws + (size_t)80 * 1024 * 1024 + (size_t)N * KPOS * sizeof(int));

    norm_kernel<<<2048, 256, 0, stream>>>(anchor, sample, Ahi, Alo, s_norm);

    dim3 ggrid(N / 128, N / 128);
    gemm_bf16<<<ggrid, 256, 0, stream>>>(Ahi, Alo, sim);

    topk_kernel<<<N / 4, 256, 0, stream>>>(sim, pos_idx, neg_idx);

    hipMemsetAsync(d_out, 0, sizeof(float), stream);
    loss_kernel<<<LOSS_BLOCKS, 256, 0, stream>>>(s_norm, pos_idx, neg_idx, out);
}

// Round 7
// 145.578 us; speedup vs baseline: 1.0015x; 1.0015x over previous
//
#include <hip/hip_runtime.h>
#include <math.h>

#define N 4096
#define D 512
#define KPOS 5
#define KNEG 10
#define NB 32               // 4096/128 block-rows
#define NTRI (NB * (NB + 1) / 2)   // 528 upper-triangle blocks

typedef short s16x8 __attribute__((ext_vector_type(8)));
typedef float f32x4 __attribute__((ext_vector_type(4)));

__device__ __forceinline__ unsigned short f2bf(float x) {
    unsigned u = __float_as_uint(x);
    unsigned r = (u + 0x7FFFu + ((u >> 16) & 1u)) >> 16;   // RNE
    return (unsigned short)r;
}
__device__ __forceinline__ float bf2f(unsigned short b) {
    return __uint_as_float(((unsigned)b) << 16);
}
__device__ __forceinline__ unsigned umax_(unsigned a, unsigned b) { return a > b ? a : b; }
__device__ __forceinline__ unsigned umin_(unsigned a, unsigned b) { return a < b ? a : b; }

// ---------------------------------------------------------------------------
// Kernel 1: normalize. anchor rows (eps 1e-8) -> bf16 hi/lo split (Ahi, Alo).
// sample rows (eps 1e-12) -> fp32 s_norm (for the loss kernel).
// ---------------------------------------------------------------------------
__global__ __launch_bounds__(256) void norm_kernel(const float* __restrict__ anchor,
                                                   const float* __restrict__ sample,
                                                   unsigned short* __restrict__ Ahi,
                                                   unsigned short* __restrict__ Alo,
                                                   float* __restrict__ s_norm) {
    const int wave = threadIdx.x >> 6, lane = threadIdx.x & 63;
    const int row = blockIdx.x * 4 + wave;
    const bool is_anchor = row < N;
    const float* in = is_anchor ? anchor + (size_t)row * D
                                : sample + (size_t)(row - N) * D;
    const float eps = is_anchor ? 1e-8f : 1e-12f;

    float v[8];
    float ss = 0.f;
#pragma unroll
    for (int e = 0; e < 8; ++e) {
        v[e] = in[lane + 64 * e];
        ss = fmaf(v[e], v[e], ss);
    }
#pragma unroll
    for (int off = 32; off > 0; off >>= 1) ss += __shfl_xor(ss, off);
    const float denom = fmaxf(sqrtf(ss), eps);

    if (is_anchor) {
        unsigned short* hi = Ahi + (size_t)row * D;
        unsigned short* lo = Alo + (size_t)row * D;
#pragma unroll
        for (int e = 0; e < 8; ++e) {
            const float x = v[e] / denom;
            const unsigned short h = f2bf(x);
            hi[lane + 64 * e] = h;
            lo[lane + 64 * e] = f2bf(x - bf2f(h));
        }
    } else {
        float* out = s_norm + (size_t)(row - N) * D;
#pragma unroll
        for (int e = 0; e < 8; ++e) out[lane + 64 * e] = v[e] / denom;
    }
}

// ---------------------------------------------------------------------------
// Kernel 2: sim = hi@hi^T + hi@lo^T + lo@hi^T (bf16 MFMA, eff. K = 1536).
// SYMMETRIC, COMPACT GRID: exactly the 528 upper-triangle blocks are
// launched (1-D grid); q -> (bi,bj) via triangular decode. Every resident
// block does real work, restoring 2-block/CU overlap that hides the
// 2-phase barrier-drain stall. Off-diagonal blocks write normal + mirror.
// ---------------------------------------------------------------------------
#define TILE (128 * 64)

__device__ __forceinline__ void stage_tile(const unsigned short* __restrict__ sA,
                                           const unsigned short* __restrict__ sB,
                                           unsigned short* As, unsigned short* Bs,
                                           int rowA, int rowB, int kl, int t) {
#pragma unroll
    for (int i = 0; i < 4; ++i) {
        const int c = i * 256 + t;                 // 16B chunk id 0..1023
        const int r = c >> 3;                      // tile row 0..127
        const int ke = ((c & 7) ^ (r & 7)) * 8;    // swizzled k-element offset
        __builtin_amdgcn_global_load_lds(
            (const __attribute__((address_space(1))) void*)(sA + (size_t)(rowA + r) * D + kl + ke),
            (__attribute__((address_space(3))) void*)(As + c * 8), 16, 0, 0);
    }
#pragma unroll
    for (int i = 0; i < 4; ++i) {
        const int c = i * 256 + t;
        const int r = c >> 3;
        const int ke = ((c & 7) ^ (r & 7)) * 8;
        __builtin_amdgcn_global_load_lds(
            (const __attribute__((address_space(1))) void*)(sB + (size_t)(rowB + r) * D + kl + ke),
            (__attribute__((address_space(3))) void*)(Bs + c * 8), 16, 0, 0);
    }
}

__global__ __launch_bounds__(256) void gemm_bf16(const unsigned short* __restrict__ Ahi,
                                                 const unsigned short* __restrict__ Alo,
                                                 float* __restrict__ C) {
    // triangular decode: q -> (bi, bj), bi<=bj. S(i) = i*(2*NB+1-i)/2.
    const int q = blockIdx.x;
    int bi = (int)((2 * NB + 1 - sqrtf((float)((2 * NB + 1) * (2 * NB + 1) - 8 * q))) * 0.5f);
    while (bi * (2 * NB + 1 - bi) / 2 > q) --bi;
    while ((bi + 1) * (2 * NB + 1 - (bi + 1)) / 2 <= q) ++bi;
    const int bj = bi + (q - bi * (2 * NB + 1 - bi) / 2);

    __shared__ __align__(16) unsigned short As[2 * TILE];   // 2 x 16 KiB
    __shared__ __align__(16) unsigned short Bs[2 * TILE];

    const int t = threadIdx.x;
    const int l = t & 63;
    const int w = t >> 6;
    const int wr = w >> 1, wc = w & 1;
    const int rowA = bi * 128;
    const int rowB = bj * 128;
    const int lrow = l & 15, lgrp = l >> 4;

    f32x4 acc[4][4];
#pragma unroll
    for (int m = 0; m < 4; ++m)
#pragma unroll
        for (int n = 0; n < 4; ++n) acc[m][n] = (f32x4){0.f, 0.f, 0.f, 0.f};

    // prologue: stage tile 0 (phase 0 = hi*hi, kl = 0)
    stage_tile(Ahi, Ahi, As, Bs, rowA, rowB, 0, t);
    __syncthreads();

    for (int kc = 0; kc < 24; ++kc) {
        const int cur = kc & 1;
        if (kc < 23) {
            const int kn = kc + 1;
            const int phase = kn >> 3;             // 0: hi*hi, 1: hi*lo, 2: lo*hi
            const int kl = (kn & 7) * 64;
            stage_tile(phase == 2 ? Alo : Ahi, phase == 1 ? Alo : Ahi,
                       As + (cur ^ 1) * TILE, Bs + (cur ^ 1) * TILE,
                       rowA, rowB, kl, t);
        }

        const char* AsB = (const char*)(As + cur * TILE);
        const char* BsB = (const char*)(Bs + cur * TILE);
#pragma unroll
        for (int kk = 0; kk < 2; ++kk) {
            s16x8 af[4], bfr[4];
#pragma unroll
            for (int m = 0; m < 4; ++m) {
                const int row = wr * 64 + m * 16 + lrow;
                af[m] = *(const s16x8*)(AsB + row * 128 + (((kk * 4 + lgrp) ^ (row & 7)) * 16));
            }
#pragma unroll
            for (int n = 0; n < 4; ++n) {
                const int row = wc * 64 + n * 16 + lrow;
                bfr[n] = *(const s16x8*)(BsB + row * 128 + (((kk * 4 + lgrp) ^ (row & 7)) * 16));
            }
#pragma unroll
            for (int m = 0; m < 4; ++m)
#pragma unroll
                for (int n = 0; n < 4; ++n)
                    acc[m][n] = __builtin_amdgcn_mfma_f32_16x16x32_bf16(af[m], bfr[n], acc[m][n], 0, 0, 0);
        }
        __syncthreads();
    }

    // C/D layout: col = lane&15, row = (lane>>4)*4 + j
#pragma unroll
    for (int m = 0; m < 4; ++m) {
#pragma unroll
        for (int n = 0; n < 4; ++n) {
            const int col = rowB + wc * 64 + n * 16 + lrow;
            const int row0 = rowA + wr * 64 + m * 16 + lgrp * 4;
#pragma unroll
            for (int j = 0; j < 4; ++j)
                C[(size_t)(row0 + j) * N + col] = acc[m][n][j];
        }
    }
    if (bi != bj) {
        // mirror block: C[col][row0..row0+3] = acc[m][n] (contiguous float4)
#pragma unroll
        for (int m = 0; m < 4; ++m) {
#pragma unroll
            for (int n = 0; n < 4; ++n) {
                const int col = rowB + wc * 64 + n * 16 + lrow;
                const int row0 = rowA + wr * 64 + m * 16 + lgrp * 4;
                *(f32x4*)&C[(size_t)col * N + row0] = acc[m][n];
            }
        }
    }
}

// ---------------------------------------------------------------------------
// Kernel 3: wave-per-row top-5 / bottom-10, branchless on packed u32 keys.
// key = (monotone_fp32_bits & 0xFFFFF000) | idx12 (idx complemented for top
// so equal truncated values resolve to the LOWER index = jax stable order).
// ---------------------------------------------------------------------------
__global__ __launch_bounds__(256) void topk_kernel(const float* __restrict__ sim,
                                                   int* __restrict__ pos_idx,
                                                   int* __restrict__ neg_idx) {
    const int w = threadIdx.x >> 6, l = threadIdx.x & 63;
    const int row = blockIdx.x * 4 + w;
    const float* s = sim + (size_t)row * N;

    unsigned tk[KPOS], bk[KNEG];
#pragma unroll
    for (int q = 0; q < KPOS; ++q) tk[q] = 0u;
#pragma unroll
    for (int q = 0; q < KNEG; ++q) bk[q] = 0xFFFFFFFFu;

    for (int e = 0; e < 16; ++e) {
        const int base = 4 * (l + 64 * e);
        const float4 v4 = *(const float4*)&s[base];
        const float vv[4] = {v4.x, v4.y, v4.z, v4.w};
#pragma unroll
        for (int j = 0; j < 4; ++j) {
            unsigned u = __float_as_uint(vv[j]);
            u ^= ((unsigned)((int)u >> 31)) | 0x80000000u;   // monotone map
            const unsigned kv = u & 0xFFFFF000u;
            const int idx = base + j;

            unsigned c = kv | (unsigned)(4095 - idx);        // top key
#pragma unroll
            for (int q = 0; q < KPOS - 1; ++q) {
                const unsigned x = umax_(tk[q], c);
                c = umin_(tk[q], c);
                tk[q] = x;
            }
            tk[KPOS - 1] = umax_(tk[KPOS - 1], c);

            c = kv | (unsigned)idx;                          // bot key
#pragma unroll
            for (int q = 0; q < KNEG - 1; ++q) {
                const unsigned x = umin_(bk[q], c);
                c = umax_(bk[q], c);
                bk[q] = x;
            }
            bk[KNEG - 1] = umax_(bk[KNEG - 1], c);
        }
    }

    // ---- merge top-5 across the wave ----
    for (int it = 0; it < KPOS; ++it) {
        unsigned m = tk[0];
#pragma unroll
        for (int off = 32; off > 0; off >>= 1) m = umax_(m, (unsigned)__shfl_xor((int)m, off));
        if (l == 0) pos_idx[row * KPOS + it] = 4095 - (int)(m & 0xFFFu);
        if (tk[0] == m) {   // unique key -> exactly one lane pops
#pragma unroll
            for (int q = 0; q < KPOS - 1; ++q) tk[q] = tk[q + 1];
            tk[KPOS - 1] = 0u;
        }
    }

    // ---- merge bottom-10 across the wave ----
    for (int it = 0; it < KNEG; ++it) {
        unsigned m = bk[0];
#pragma unroll
        for (int off = 32; off > 0; off >>= 1) m = umin_(m, (unsigned)__shfl_xor((int)m, off));
        if (l == 0) neg_idx[row * KNEG + it] = (int)(m & 0xFFFu);
        if (bk[0] == m) {
#pragma unroll
            for (int q = 0; q < KNEG - 1; ++q) bk[q] = bk[q + 1];
            bk[KNEG - 1] = 0xFFFFFFFFu;
        }
    }
}

// ---------------------------------------------------------------------------
// Kernel 4: InfoNCE loss. 320 blocks x 4 waves x 16 rows; one atomic/block.
// ---------------------------------------------------------------------------
#define LOSS_BLOCKS 320
#define ROWS_PER_WAVE 16

__global__ __launch_bounds__(256) void loss_kernel(const float* __restrict__ s_norm,
                                                   const int* __restrict__ pos_idx,
                                                   const int* __restrict__ neg_idx,
                                                   float* __restrict__ out) {
    __shared__ float wsum[4];
    const int wave = threadIdx.x >> 6, lane = threadIdx.x & 63;
    const int gwave = blockIdx.x * 4 + wave;

    float lsum = 0.f;
    for (int rr = 0; rr < ROWS_PER_WAVE; ++rr) {
        const int j = gwave * ROWS_PER_WAVE + rr;
        const int ia = j / 5;
        const int p = j - ia * 5;
        const int iq = j & (N - 1);

        const float* q = s_norm + (size_t)iq * D;
        float qv[8];
#pragma unroll
        for (int e = 0; e < 8; ++e) qv[e] = q[lane + 64 * e];

        const int pi = pos_idx[ia * KPOS + p];
        const float* pv = s_norm + (size_t)pi * D;
        float accp = 0.f;
#pragma unroll
        for (int e = 0; e < 8; ++e) accp = fmaf(qv[e], pv[lane + 64 * e], accp);

        float accn[KNEG];
#pragma unroll
        for (int k = 0; k < KNEG; ++k) {
            const float* nv = s_norm + (size_t)neg_idx[ia * KNEG + k] * D;
            float a = 0.f;
#pragma unroll
            for (int e = 0; e < 8; ++e) a = fmaf(qv[e], nv[lane + 64 * e], a);
            accn[k] = a;
        }

#pragma unroll
        for (int off = 32; off > 0; off >>= 1) {
            accp += __shfl_xor(accp, off);
#pragma unroll
            for (int k = 0; k < KNEG; ++k) accn[k] += __shfl_xor(accn[k], off);
        }

        const float l0 = accp * 10.f;
        float m = l0;
#pragma unroll
        for (int k = 0; k < KNEG; ++k) m = fmaxf(m, accn[k] * 10.f);
        float ssum = expf(l0 - m);
#pragma unroll
        for (int k = 0; k < KNEG; ++k) ssum += expf(accn[k] * 10.f - m);
        lsum += logf(ssum) + m - l0;
    }

    if (lane == 0) wsum[wave] = lsum;
    __syncthreads();
    if (threadIdx.x == 0) {
        const float total = wsum[0] + wsum[1] + wsum[2] + wsum[3];
        atomicAdd(out, total * (1.0f / (float)(N * KPOS)));
    }
}

// ---------------------------------------------------------------------------
extern "C" void kernel_launch(void* const* d_in, const int* in_sizes, int n_in,
                              void* d_out, int out_size, void* d_ws, size_t ws_size,
                              hipStream_t stream) {
    const float* anchor = (const float*)d_in[0];
    const float* sample = (const float*)d_in[1];
    float* out = (float*)d_out;

    char* ws = (char*)d_ws;
    unsigned short* Ahi = (unsigned short*)ws;                              // 4 MiB
    unsigned short* Alo = (unsigned short*)(ws + (size_t)4 * 1024 * 1024);  // 4 MiB
    float* s_norm = (float*)(ws + (size_t)8 * 1024 * 1024);                 // 8 MiB
    float* sim    = (float*)(ws + (size_t)16 * 1024 * 1024);                // 64 MiB
    int* pos_idx  = (int*)(ws + (size_t)80 * 1024 * 1024);
    int* neg_idx  = (int*)(ws + (size_t)80 * 1024 * 1024 + (size_t)N * KPOS * sizeof(int));

    norm_kernel<<<2048, 256, 0, stream>>>(anchor, sample, Ahi, Alo, s_norm);

    gemm_bf16<<<NTRI, 256, 0, stream>>>(Ahi, Alo, sim);

    topk_kernel<<<N / 4, 256, 0, stream>>>(sim, pos_idx, neg_idx);

    hipMemsetAsync(d_out, 0, sizeof(float), stream);
    loss_kernel<<<LOSS_BLOCKS, 256, 0, stream>>>(s_norm, pos_idx, neg_idx, out);
}

// Round 8
// 131.558 us; speedup vs baseline: 1.1082x; 1.1066x over previous
//
#include <hip/hip_runtime.h>
#include <math.h>

#define N 4096
#define D 512
#define KPOS 5
#define KNEG 10
#define NB 32                      // 4096/128 block-rows
#define NTRI (NB * (NB + 1) / 2)   // 528 upper-triangle blocks

typedef short s16x8 __attribute__((ext_vector_type(8)));
typedef unsigned short u16x8 __attribute__((ext_vector_type(8)));
typedef float f32x4 __attribute__((ext_vector_type(4)));

__device__ __forceinline__ unsigned short f2bf(float x) {
    unsigned u = __float_as_uint(x);
    unsigned r = (u + 0x7FFFu + ((u >> 16) & 1u)) >> 16;   // RNE
    return (unsigned short)r;
}
__device__ __forceinline__ float bf2f(unsigned short b) {
    return __uint_as_float(((unsigned)b) << 16);
}
__device__ __forceinline__ unsigned umax_(unsigned a, unsigned b) { return a > b ? a : b; }
__device__ __forceinline__ unsigned umin_(unsigned a, unsigned b) { return a < b ? a : b; }

// ---------------------------------------------------------------------------
// Kernel 1: normalize. anchor rows (eps 1e-8) -> bf16 hi/lo split (Ahi, Alo).
// sample rows (eps 1e-12) -> bf16 s_norm (for the loss kernel).
// ---------------------------------------------------------------------------
__global__ __launch_bounds__(256) void norm_kernel(const float* __restrict__ anchor,
                                                   const float* __restrict__ sample,
                                                   unsigned short* __restrict__ Ahi,
                                                   unsigned short* __restrict__ Alo,
                                                   unsigned short* __restrict__ s_norm) {
    const int wave = threadIdx.x >> 6, lane = threadIdx.x & 63;
    const int row = blockIdx.x * 4 + wave;
    const bool is_anchor = row < N;
    const float* in = is_anchor ? anchor + (size_t)row * D
                                : sample + (size_t)(row - N) * D;
    const float eps = is_anchor ? 1e-8f : 1e-12f;

    float v[8];
    float ss = 0.f;
#pragma unroll
    for (int e = 0; e < 8; ++e) {
        v[e] = in[lane + 64 * e];
        ss = fmaf(v[e], v[e], ss);
    }
#pragma unroll
    for (int off = 32; off > 0; off >>= 1) ss += __shfl_xor(ss, off);
    const float denom = fmaxf(sqrtf(ss), eps);

    if (is_anchor) {
        unsigned short* hi = Ahi + (size_t)row * D;
        unsigned short* lo = Alo + (size_t)row * D;
#pragma unroll
        for (int e = 0; e < 8; ++e) {
            const float x = v[e] / denom;
            const unsigned short h = f2bf(x);
            hi[lane + 64 * e] = h;
            lo[lane + 64 * e] = f2bf(x - bf2f(h));
        }
    } else {
        unsigned short* out = s_norm + (size_t)(row - N) * D;
#pragma unroll
        for (int e = 0; e < 8; ++e) out[lane + 64 * e] = f2bf(v[e] / denom);
    }
}

// ---------------------------------------------------------------------------
// Kernel 2: sim = hi@hi^T + hi@lo^T + lo@hi^T (bf16 MFMA, eff. K = 1536).
// Upper-triangle compact grid (528 blocks), SINGLE-buffered LDS (32 KiB ->
// 5 blocks/CU co-resident; m97 structure — implicit multi-block overlap
// hides the stage+drain, m114/m132). stage -> vmcnt -> barrier -> compute.
// T2 XOR swizzle via pre-swizzled global source (rule #21). Output bf16,
// off-diagonal blocks write normal + transposed mirror.
// ---------------------------------------------------------------------------
#define TILE (128 * 64)

__device__ __forceinline__ void stage_tile(const unsigned short* __restrict__ sA,
                                           const unsigned short* __restrict__ sB,
                                           unsigned short* As, unsigned short* Bs,
                                           int rowA, int rowB, int kl, int t) {
#pragma unroll
    for (int i = 0; i < 4; ++i) {
        const int c = i * 256 + t;                 // 16B chunk id 0..1023
        const int r = c >> 3;                      // tile row 0..127
        const int ke = ((c & 7) ^ (r & 7)) * 8;    // swizzled k-element offset
        __builtin_amdgcn_global_load_lds(
            (const __attribute__((address_space(1))) void*)(sA + (size_t)(rowA + r) * D + kl + ke),
            (__attribute__((address_space(3))) void*)(As + c * 8), 16, 0, 0);
    }
#pragma unroll
    for (int i = 0; i < 4; ++i) {
        const int c = i * 256 + t;
        const int r = c >> 3;
        const int ke = ((c & 7) ^ (r & 7)) * 8;
        __builtin_amdgcn_global_load_lds(
            (const __attribute__((address_space(1))) void*)(sB + (size_t)(rowB + r) * D + kl + ke),
            (__attribute__((address_space(3))) void*)(Bs + c * 8), 16, 0, 0);
    }
}

__global__ __launch_bounds__(256) void gemm_bf16(const unsigned short* __restrict__ Ahi,
                                                 const unsigned short* __restrict__ Alo,
                                                 unsigned short* __restrict__ C) {
    // triangular decode: q -> (bi, bj), bi<=bj. S(i) = i*(2*NB+1-i)/2.
    const int q = blockIdx.x;
    int bi = (int)((2 * NB + 1 - sqrtf((float)((2 * NB + 1) * (2 * NB + 1) - 8 * q))) * 0.5f);
    while (bi * (2 * NB + 1 - bi) / 2 > q) --bi;
    while ((bi + 1) * (2 * NB + 1 - (bi + 1)) / 2 <= q) ++bi;
    const int bj = bi + (q - bi * (2 * NB + 1 - bi) / 2);

    __shared__ __align__(16) unsigned short As[TILE];   // 16 KiB
    __shared__ __align__(16) unsigned short Bs[TILE];   // 16 KiB

    const int t = threadIdx.x;
    const int l = t & 63;
    const int w = t >> 6;
    const int wr = w >> 1, wc = w & 1;
    const int rowA = bi * 128;
    const int rowB = bj * 128;
    const int lrow = l & 15, lgrp = l >> 4;

    f32x4 acc[4][4];
#pragma unroll
    for (int m = 0; m < 4; ++m)
#pragma unroll
        for (int n = 0; n < 4; ++n) acc[m][n] = (f32x4){0.f, 0.f, 0.f, 0.f};

    for (int kc = 0; kc < 24; ++kc) {
        const int phase = kc >> 3;                 // 0: hi*hi, 1: hi*lo, 2: lo*hi
        const int kl = (kc & 7) * 64;
        if (kc) __syncthreads();                   // protect buffer from prev readers
        stage_tile(phase == 2 ? Alo : Ahi, phase == 1 ? Alo : Ahi,
                   As, Bs, rowA, rowB, kl, t);
        asm volatile("s_waitcnt vmcnt(0)");
        __syncthreads();

#pragma unroll
        for (int kk = 0; kk < 2; ++kk) {
            s16x8 af[4], bfr[4];
#pragma unroll
            for (int m = 0; m < 4; ++m) {
                const int row = wr * 64 + m * 16 + lrow;
                af[m] = *(const s16x8*)((const char*)As + row * 128 + (((kk * 4 + lgrp) ^ (row & 7)) * 16));
            }
#pragma unroll
            for (int n = 0; n < 4; ++n) {
                const int row = wc * 64 + n * 16 + lrow;
                bfr[n] = *(const s16x8*)((const char*)Bs + row * 128 + (((kk * 4 + lgrp) ^ (row & 7)) * 16));
            }
#pragma unroll
            for (int m = 0; m < 4; ++m)
#pragma unroll
                for (int n = 0; n < 4; ++n)
                    acc[m][n] = __builtin_amdgcn_mfma_f32_16x16x32_bf16(af[m], bfr[n], acc[m][n], 0, 0, 0);
        }
    }

    // C/D layout: col = lane&15, row = (lane>>4)*4 + j ; store bf16.
#pragma unroll
    for (int m = 0; m < 4; ++m) {
#pragma unroll
        for (int n = 0; n < 4; ++n) {
            const int col = rowB + wc * 64 + n * 16 + lrow;
            const int row0 = rowA + wr * 64 + m * 16 + lgrp * 4;
#pragma unroll
            for (int j = 0; j < 4; ++j)
                C[(size_t)(row0 + j) * N + col] = f2bf(acc[m][n][j]);
        }
    }
    if (bi != bj) {
        // mirror block: C[col][row0..row0+3] — 4 consecutive bf16 = 8B store.
#pragma unroll
        for (int m = 0; m < 4; ++m) {
#pragma unroll
            for (int n = 0; n < 4; ++n) {
                const int col = rowB + wc * 64 + n * 16 + lrow;
                const int row0 = rowA + wr * 64 + m * 16 + lgrp * 4;
                ushort4 pk;
                pk.x = f2bf(acc[m][n][0]);
                pk.y = f2bf(acc[m][n][1]);
                pk.z = f2bf(acc[m][n][2]);
                pk.w = f2bf(acc[m][n][3]);
                *(ushort4*)&C[(size_t)col * N + row0] = pk;
            }
        }
    }
}

// ---------------------------------------------------------------------------
// Kernel 3: wave-per-row top-5 / bottom-10 over bf16 sim, branchless packed
// u32 keys: key = monotone(bf16<<16) & 0xFFFF0000 | idx12 (idx complemented
// for top so ties resolve to LOWER index = jax stable order).
// ---------------------------------------------------------------------------
__global__ __launch_bounds__(256) void topk_kernel(const unsigned short* __restrict__ sim,
                                                   int* __restrict__ pos_idx,
                                                   int* __restrict__ neg_idx) {
    const int w = threadIdx.x >> 6, l = threadIdx.x & 63;
    const int row = blockIdx.x * 4 + w;
    const unsigned short* s = sim + (size_t)row * N;

    unsigned tk[KPOS], bk[KNEG];
#pragma unroll
    for (int q = 0; q < KPOS; ++q) tk[q] = 0u;
#pragma unroll
    for (int q = 0; q < KNEG; ++q) bk[q] = 0xFFFFFFFFu;

    for (int e = 0; e < 8; ++e) {
        const int base = 8 * (l + 64 * e);
        const u16x8 v8 = *(const u16x8*)&s[base];
#pragma unroll
        for (int j = 0; j < 8; ++j) {
            unsigned u = ((unsigned)v8[j]) << 16;
            u ^= ((unsigned)((int)u >> 31)) | 0x80000000u;   // monotone map
            const unsigned kv = u & 0xFFFF0000u;
            const int idx = base + j;

            unsigned c = kv | (unsigned)(4095 - idx);        // top key
#pragma unroll
            for (int q = 0; q < KPOS - 1; ++q) {
                const unsigned x = umax_(tk[q], c);
                c = umin_(tk[q], c);
                tk[q] = x;
            }
            tk[KPOS - 1] = umax_(tk[KPOS - 1], c);

            c = kv | (unsigned)idx;                          // bot key
#pragma unroll
            for (int q = 0; q < KNEG - 1; ++q) {
                const unsigned x = umin_(bk[q], c);
                c = umax_(bk[q], c);
                bk[q] = x;
            }
            bk[KNEG - 1] = umax_(bk[KNEG - 1], c);
        }
    }

    // ---- merge top-5 across the wave ----
    for (int it = 0; it < KPOS; ++it) {
        unsigned m = tk[0];
#pragma unroll
        for (int off = 32; off > 0; off >>= 1) m = umax_(m, (unsigned)__shfl_xor((int)m, off));
        if (l == 0) pos_idx[row * KPOS + it] = 4095 - (int)(m & 0xFFFu);
        if (tk[0] == m) {   // unique key -> exactly one lane pops
#pragma unroll
            for (int q = 0; q < KPOS - 1; ++q) tk[q] = tk[q + 1];
            tk[KPOS - 1] = 0u;
        }
    }

    // ---- merge bottom-10 across the wave ----
    for (int it = 0; it < KNEG; ++it) {
        unsigned m = bk[0];
#pragma unroll
        for (int off = 32; off > 0; off >>= 1) m = umin_(m, (unsigned)__shfl_xor((int)m, off));
        if (l == 0) neg_idx[row * KNEG + it] = (int)(m & 0xFFFu);
        if (bk[0] == m) {
#pragma unroll
            for (int q = 0; q < KNEG - 1; ++q) bk[q] = bk[q + 1];
            bk[KNEG - 1] = 0xFFFFFFFFu;
        }
    }
}

// ---------------------------------------------------------------------------
// Kernel 4: InfoNCE loss over bf16 s_norm. 320 blocks x 4 waves x 16 rows;
// one atomicAdd per block. Lane i holds elements [8i, 8i+8) (order-invariant
// dot). Logits are uniform across lanes after the shuffle reduce.
// ---------------------------------------------------------------------------
#define LOSS_BLOCKS 320
#define ROWS_PER_WAVE 16

__global__ __launch_bounds__(256) void loss_kernel(const unsigned short* __restrict__ s_norm,
                                                   const int* __restrict__ pos_idx,
                                                   const int* __restrict__ neg_idx,
                                                   float* __restrict__ out) {
    __shared__ float wsum[4];
    const int wave = threadIdx.x >> 6, lane = threadIdx.x & 63;
    const int gwave = blockIdx.x * 4 + wave;

    float lsum = 0.f;
    for (int rr = 0; rr < ROWS_PER_WAVE; ++rr) {
        const int j = gwave * ROWS_PER_WAVE + rr;
        const int ia = j / 5;
        const int p = j - ia * 5;
        const int iq = j & (N - 1);

        const u16x8 qr = *(const u16x8*)(s_norm + (size_t)iq * D + lane * 8);
        float qv[8];
#pragma unroll
        for (int e = 0; e < 8; ++e) qv[e] = bf2f(qr[e]);

        const int pi = pos_idx[ia * KPOS + p];
        const u16x8 pr = *(const u16x8*)(s_norm + (size_t)pi * D + lane * 8);
        float accp = 0.f;
#pragma unroll
        for (int e = 0; e < 8; ++e) accp = fmaf(qv[e], bf2f(pr[e]), accp);

        float accn[KNEG];
#pragma unroll
        for (int k = 0; k < KNEG; ++k) {
            const u16x8 nr = *(const u16x8*)(s_norm + (size_t)neg_idx[ia * KNEG + k] * D + lane * 8);
            float a = 0.f;
#pragma unroll
            for (int e = 0; e < 8; ++e) a = fmaf(qv[e], bf2f(nr[e]), a);
            accn[k] = a;
        }

#pragma unroll
        for (int off = 32; off > 0; off >>= 1) {
            accp += __shfl_xor(accp, off);
#pragma unroll
            for (int k = 0; k < KNEG; ++k) accn[k] += __shfl_xor(accn[k], off);
        }

        const float l0 = accp * 10.f;
        float m = l0;
#pragma unroll
        for (int k = 0; k < KNEG; ++k) m = fmaxf(m, accn[k] * 10.f);
        float ssum = expf(l0 - m);
#pragma unroll
        for (int k = 0; k < KNEG; ++k) ssum += expf(accn[k] * 10.f - m);
        lsum += logf(ssum) + m - l0;
    }

    if (lane == 0) wsum[wave] = lsum;
    __syncthreads();
    if (threadIdx.x == 0) {
        const float total = wsum[0] + wsum[1] + wsum[2] + wsum[3];
        atomicAdd(out, total * (1.0f / (float)(N * KPOS)));
    }
}

// ---------------------------------------------------------------------------
extern "C" void kernel_launch(void* const* d_in, const int* in_sizes, int n_in,
                              void* d_out, int out_size, void* d_ws, size_t ws_size,
                              hipStream_t stream) {
    const float* anchor = (const float*)d_in[0];
    const float* sample = (const float*)d_in[1];
    float* out = (float*)d_out;

    char* ws = (char*)d_ws;
    unsigned short* Ahi    = (unsigned short*)ws;                               // 4 MiB
    unsigned short* Alo    = (unsigned short*)(ws + (size_t)4 * 1024 * 1024);   // 4 MiB
    unsigned short* s_norm = (unsigned short*)(ws + (size_t)8 * 1024 * 1024);   // 4 MiB
    unsigned short* sim    = (unsigned short*)(ws + (size_t)12 * 1024 * 1024);  // 32 MiB
    int* pos_idx  = (int*)(ws + (size_t)44 * 1024 * 1024);
    int* neg_idx  = (int*)(ws + (size_t)44 * 1024 * 1024 + (size_t)N * KPOS * sizeof(int));

    norm_kernel<<<2048, 256, 0, stream>>>(anchor, sample, Ahi, Alo, s_norm);

    gemm_bf16<<<NTRI, 256, 0, stream>>>(Ahi, Alo, sim);

    topk_kernel<<<N / 4, 256, 0, stream>>>(sim, pos_idx, neg_idx);

    hipMemsetAsync(d_out, 0, sizeof(float), stream);
    loss_kernel<<<LOSS_BLOCKS, 256, 0, stream>>>(s_norm, pos_idx, neg_idx, out);
}

// Round 9
// 97.863 us; speedup vs baseline: 1.4898x; 1.3443x over previous
//
#include <hip/hip_runtime.h>
#include <math.h>

#define N 4096
#define D 512
#define KPOS 5
#define KNEG 10
#define NB 32                      // 4096/128 block-rows
#define NTRI (NB * (NB + 1) / 2)   // 528 upper-triangle blocks

typedef short s16x8 __attribute__((ext_vector_type(8)));
typedef unsigned short u16x8 __attribute__((ext_vector_type(8)));
typedef float f32x4 __attribute__((ext_vector_type(4)));

__device__ __forceinline__ unsigned short f2bf(float x) {
    unsigned u = __float_as_uint(x);
    unsigned r = (u + 0x7FFFu + ((u >> 16) & 1u)) >> 16;   // RNE
    return (unsigned short)r;
}
__device__ __forceinline__ float bf2f(unsigned short b) {
    return __uint_as_float(((unsigned)b) << 16);
}
__device__ __forceinline__ unsigned umax_(unsigned a, unsigned b) { return a > b ? a : b; }
__device__ __forceinline__ unsigned umin_(unsigned a, unsigned b) { return a < b ? a : b; }

// ---------------------------------------------------------------------------
// Kernel 1: normalize. anchor rows (eps 1e-8) -> bf16 A (for MFMA GEMM).
// sample rows (eps 1e-12) -> bf16 s_norm (for the loss kernel).
// ---------------------------------------------------------------------------
__global__ __launch_bounds__(256) void norm_kernel(const float* __restrict__ anchor,
                                                   const float* __restrict__ sample,
                                                   unsigned short* __restrict__ Abf,
                                                   unsigned short* __restrict__ s_norm) {
    const int wave = threadIdx.x >> 6, lane = threadIdx.x & 63;
    const int row = blockIdx.x * 4 + wave;
    const bool is_anchor = row < N;
    const float* in = is_anchor ? anchor + (size_t)row * D
                                : sample + (size_t)(row - N) * D;
    const float eps = is_anchor ? 1e-8f : 1e-12f;

    float v[8];
    float ss = 0.f;
#pragma unroll
    for (int e = 0; e < 8; ++e) {
        v[e] = in[lane + 64 * e];
        ss = fmaf(v[e], v[e], ss);
    }
#pragma unroll
    for (int off = 32; off > 0; off >>= 1) ss += __shfl_xor(ss, off);
    const float denom = fmaxf(sqrtf(ss), eps);

    unsigned short* out = is_anchor ? Abf + (size_t)row * D
                                    : s_norm + (size_t)(row - N) * D;
#pragma unroll
    for (int e = 0; e < 8; ++e) out[lane + 64 * e] = f2bf(v[e] / denom);
}

// ---------------------------------------------------------------------------
// Kernel 2: sim = A@A^T, bf16 MFMA, K = 512. Upper-triangle compact grid
// (528 blocks) with T1 bijective XCD chunk swizzle (528 % 8 == 0 -> each
// XCD gets 66 contiguous triangle jobs = contiguous bi-rows -> L2 panel
// reuse). 128x128 tile, BK=64, double-buffered LDS with prefetch-before-
// compute (r5 structure: the post-compute __syncthreads drains vmcnt, so
// the prefetch latency hides under the MFMA phase). T2 XOR swizzle via
// pre-swizzled global source (rule #21). bf16 output, off-diagonal blocks
// write normal + transposed mirror (ushort4).
// ---------------------------------------------------------------------------
#define TILE (128 * 64)

__device__ __forceinline__ void stage_tile(const unsigned short* __restrict__ A,
                                           unsigned short* As, unsigned short* Bs,
                                           int rowA, int rowB, int kl, int t) {
#pragma unroll
    for (int i = 0; i < 4; ++i) {
        const int c = i * 256 + t;                 // 16B chunk id 0..1023
        const int r = c >> 3;                      // tile row 0..127
        const int ke = ((c & 7) ^ (r & 7)) * 8;    // swizzled k-element offset
        __builtin_amdgcn_global_load_lds(
            (const __attribute__((address_space(1))) void*)(A + (size_t)(rowA + r) * D + kl + ke),
            (__attribute__((address_space(3))) void*)(As + c * 8), 16, 0, 0);
    }
#pragma unroll
    for (int i = 0; i < 4; ++i) {
        const int c = i * 256 + t;
        const int r = c >> 3;
        const int ke = ((c & 7) ^ (r & 7)) * 8;
        __builtin_amdgcn_global_load_lds(
            (const __attribute__((address_space(1))) void*)(A + (size_t)(rowB + r) * D + kl + ke),
            (__attribute__((address_space(3))) void*)(Bs + c * 8), 16, 0, 0);
    }
}

__global__ __launch_bounds__(256) void gemm_bf16(const unsigned short* __restrict__ Abf,
                                                 unsigned short* __restrict__ C) {
    // T1: XCD chunk swizzle (bijective since NTRI % 8 == 0).
    const int q = (blockIdx.x % 8) * (NTRI / 8) + blockIdx.x / 8;
    // triangular decode: q -> (bi, bj), bi<=bj. S(i) = i*(2*NB+1-i)/2.
    int bi = (int)((2 * NB + 1 - sqrtf((float)((2 * NB + 1) * (2 * NB + 1) - 8 * q))) * 0.5f);
    while (bi * (2 * NB + 1 - bi) / 2 > q) --bi;
    while ((bi + 1) * (2 * NB + 1 - (bi + 1)) / 2 <= q) ++bi;
    const int bj = bi + (q - bi * (2 * NB + 1 - bi) / 2);

    __shared__ __align__(16) unsigned short As[2 * TILE];   // 2 x 16 KiB
    __shared__ __align__(16) unsigned short Bs[2 * TILE];   // 2 x 16 KiB

    const int t = threadIdx.x;
    const int l = t & 63;
    const int w = t >> 6;
    const int wr = w >> 1, wc = w & 1;
    const int rowA = bi * 128;
    const int rowB = bj * 128;
    const int lrow = l & 15, lgrp = l >> 4;

    f32x4 acc[4][4];
#pragma unroll
    for (int m = 0; m < 4; ++m)
#pragma unroll
        for (int n = 0; n < 4; ++n) acc[m][n] = (f32x4){0.f, 0.f, 0.f, 0.f};

    // prologue: stage k-step 0 into buffer 0
    stage_tile(Abf, As, Bs, rowA, rowB, 0, t);
    __syncthreads();   // drains vmcnt (compiler emits s_waitcnt before s_barrier)

    for (int kc = 0; kc < 8; ++kc) {
        const int cur = kc & 1;
        if (kc < 7)
            stage_tile(Abf, As + (cur ^ 1) * TILE, Bs + (cur ^ 1) * TILE,
                       rowA, rowB, (kc + 1) * 64, t);

        const char* AsB = (const char*)(As + cur * TILE);
        const char* BsB = (const char*)(Bs + cur * TILE);
#pragma unroll
        for (int kk = 0; kk < 2; ++kk) {
            s16x8 af[4], bfr[4];
#pragma unroll
            for (int m = 0; m < 4; ++m) {
                const int row = wr * 64 + m * 16 + lrow;
                af[m] = *(const s16x8*)(AsB + row * 128 + (((kk * 4 + lgrp) ^ (row & 7)) * 16));
            }
#pragma unroll
            for (int n = 0; n < 4; ++n) {
                const int row = wc * 64 + n * 16 + lrow;
                bfr[n] = *(const s16x8*)(BsB + row * 128 + (((kk * 4 + lgrp) ^ (row & 7)) * 16));
            }
#pragma unroll
            for (int m = 0; m < 4; ++m)
#pragma unroll
                for (int n = 0; n < 4; ++n)
                    acc[m][n] = __builtin_amdgcn_mfma_f32_16x16x32_bf16(af[m], bfr[n], acc[m][n], 0, 0, 0);
        }
        // drains this iter's prefetch and fences prev-buffer reuse.
        __syncthreads();
    }

    // C/D layout: col = lane&15, row = (lane>>4)*4 + j ; store bf16.
#pragma unroll
    for (int m = 0; m < 4; ++m) {
#pragma unroll
        for (int n = 0; n < 4; ++n) {
            const int col = rowB + wc * 64 + n * 16 + lrow;
            const int row0 = rowA + wr * 64 + m * 16 + lgrp * 4;
#pragma unroll
            for (int j = 0; j < 4; ++j)
                C[(size_t)(row0 + j) * N + col] = f2bf(acc[m][n][j]);
        }
    }
    if (bi != bj) {
        // mirror block: C[col][row0..row0+3] — 4 consecutive bf16 = 8B store.
#pragma unroll
        for (int m = 0; m < 4; ++m) {
#pragma unroll
            for (int n = 0; n < 4; ++n) {
                const int col = rowB + wc * 64 + n * 16 + lrow;
                const int row0 = rowA + wr * 64 + m * 16 + lgrp * 4;
                ushort4 pk;
                pk.x = f2bf(acc[m][n][0]);
                pk.y = f2bf(acc[m][n][1]);
                pk.z = f2bf(acc[m][n][2]);
                pk.w = f2bf(acc[m][n][3]);
                *(ushort4*)&C[(size_t)col * N + row0] = pk;
            }
        }
    }
}

// ---------------------------------------------------------------------------
// Kernel 3: wave-per-row top-5 / bottom-10 over bf16 sim, branchless packed
// u32 keys: key = monotone(bf16<<16) & 0xFFFF0000 | idx12 (idx complemented
// for top so ties resolve to LOWER index = jax stable order).
// Block 0 thread 0 also zeroes the loss accumulator (topk precedes loss).
// ---------------------------------------------------------------------------
__global__ __launch_bounds__(256) void topk_kernel(const unsigned short* __restrict__ sim,
                                                   int* __restrict__ pos_idx,
                                                   int* __restrict__ neg_idx,
                                                   float* __restrict__ out) {
    if (blockIdx.x == 0 && threadIdx.x == 0) *out = 0.f;
    const int w = threadIdx.x >> 6, l = threadIdx.x & 63;
    const int row = blockIdx.x * 4 + w;
    const unsigned short* s = sim + (size_t)row * N;

    unsigned tk[KPOS], bk[KNEG];
#pragma unroll
    for (int q = 0; q < KPOS; ++q) tk[q] = 0u;
#pragma unroll
    for (int q = 0; q < KNEG; ++q) bk[q] = 0xFFFFFFFFu;

    for (int e = 0; e < 8; ++e) {
        const int base = 8 * (l + 64 * e);
        const u16x8 v8 = *(const u16x8*)&s[base];
#pragma unroll
        for (int j = 0; j < 8; ++j) {
            unsigned u = ((unsigned)v8[j]) << 16;
            u ^= ((unsigned)((int)u >> 31)) | 0x80000000u;   // monotone map
            const unsigned kv = u & 0xFFFF0000u;
            const int idx = base + j;

            unsigned c = kv | (unsigned)(4095 - idx);        // top key
#pragma unroll
            for (int q = 0; q < KPOS - 1; ++q) {
                const unsigned x = umax_(tk[q], c);
                c = umin_(tk[q], c);
                tk[q] = x;
            }
            tk[KPOS - 1] = umax_(tk[KPOS - 1], c);

            c = kv | (unsigned)idx;                          // bot key
#pragma unroll
            for (int q = 0; q < KNEG - 1; ++q) {
                const unsigned x = umin_(bk[q], c);
                c = umax_(bk[q], c);
                bk[q] = x;
            }
            bk[KNEG - 1] = umax_(bk[KNEG - 1], c);
        }
    }

    // ---- merge top-5 across the wave ----
    for (int it = 0; it < KPOS; ++it) {
        unsigned m = tk[0];
#pragma unroll
        for (int off = 32; off > 0; off >>= 1) m = umax_(m, (unsigned)__shfl_xor((int)m, off));
        if (l == 0) pos_idx[row * KPOS + it] = 4095 - (int)(m & 0xFFFu);
        if (tk[0] == m) {   // unique key -> exactly one lane pops
#pragma unroll
            for (int q = 0; q < KPOS - 1; ++q) tk[q] = tk[q + 1];
            tk[KPOS - 1] = 0u;
        }
    }

    // ---- merge bottom-10 across the wave ----
    for (int it = 0; it < KNEG; ++it) {
        unsigned m = bk[0];
#pragma unroll
        for (int off = 32; off > 0; off >>= 1) m = umin_(m, (unsigned)__shfl_xor((int)m, off));
        if (l == 0) neg_idx[row * KNEG + it] = (int)(m & 0xFFFu);
        if (bk[0] == m) {
#pragma unroll
            for (int q = 0; q < KNEG - 1; ++q) bk[q] = bk[q + 1];
            bk[KNEG - 1] = 0xFFFFFFFFu;
        }
    }
}

// ---------------------------------------------------------------------------
// Kernel 4: InfoNCE loss over bf16 s_norm. 320 blocks x 4 waves x 16 rows;
// one atomicAdd per block.
// ---------------------------------------------------------------------------
#define LOSS_BLOCKS 320
#define ROWS_PER_WAVE 16

__global__ __launch_bounds__(256) void loss_kernel(const unsigned short* __restrict__ s_norm,
                                                   const int* __restrict__ pos_idx,
                                                   const int* __restrict__ neg_idx,
                                                   float* __restrict__ out) {
    __shared__ float wsum[4];
    const int wave = threadIdx.x >> 6, lane = threadIdx.x & 63;
    const int gwave = blockIdx.x * 4 + wave;

    float lsum = 0.f;
    for (int rr = 0; rr < ROWS_PER_WAVE; ++rr) {
        const int j = gwave * ROWS_PER_WAVE + rr;
        const int ia = j / 5;
        const int p = j - ia * 5;
        const int iq = j & (N - 1);

        const u16x8 qr = *(const u16x8*)(s_norm + (size_t)iq * D + lane * 8);
        float qv[8];
#pragma unroll
        for (int e = 0; e < 8; ++e) qv[e] = bf2f(qr[e]);

        const int pi = pos_idx[ia * KPOS + p];
        const u16x8 pr = *(const u16x8*)(s_norm + (size_t)pi * D + lane * 8);
        float accp = 0.f;
#pragma unroll
        for (int e = 0; e < 8; ++e) accp = fmaf(qv[e], bf2f(pr[e]), accp);

        float accn[KNEG];
#pragma unroll
        for (int k = 0; k < KNEG; ++k) {
            const u16x8 nr = *(const u16x8*)(s_norm + (size_t)neg_idx[ia * KNEG + k] * D + lane * 8);
            float a = 0.f;
#pragma unroll
            for (int e = 0; e < 8; ++e) a = fmaf(qv[e], bf2f(nr[e]), a);
            accn[k] = a;
        }

#pragma unroll
        for (int off = 32; off > 0; off >>= 1) {
            accp += __shfl_xor(accp, off);
#pragma unroll
            for (int k = 0; k < KNEG; ++k) accn[k] += __shfl_xor(accn[k], off);
        }

        const float l0 = accp * 10.f;
        float m = l0;
#pragma unroll
        for (int k = 0; k < KNEG; ++k) m = fmaxf(m, accn[k] * 10.f);
        float ssum = expf(l0 - m);
#pragma unroll
        for (int k = 0; k < KNEG; ++k) ssum += expf(accn[k] * 10.f - m);
        lsum += logf(ssum) + m - l0;
    }

    if (lane == 0) wsum[wave] = lsum;
    __syncthreads();
    if (threadIdx.x == 0) {
        const float total = wsum[0] + wsum[1] + wsum[2] + wsum[3];
        atomicAdd(out, total * (1.0f / (float)(N * KPOS)));
    }
}

// ---------------------------------------------------------------------------
extern "C" void kernel_launch(void* const* d_in, const int* in_sizes, int n_in,
                              void* d_out, int out_size, void* d_ws, size_t ws_size,
                              hipStream_t stream) {
    const float* anchor = (const float*)d_in[0];
    const float* sample = (const float*)d_in[1];
    float* out = (float*)d_out;

    char* ws = (char*)d_ws;
    unsigned short* Abf    = (unsigned short*)ws;                               // 4 MiB
    unsigned short* s_norm = (unsigned short*)(ws + (size_t)4 * 1024 * 1024);   // 4 MiB
    unsigned short* sim    = (unsigned short*)(ws + (size_t)8 * 1024 * 1024);   // 32 MiB
    int* pos_idx  = (int*)(ws + (size_t)40 * 1024 * 1024);
    int* neg_idx  = (int*)(ws + (size_t)40 * 1024 * 1024 + (size_t)N * KPOS * sizeof(int));

    norm_kernel<<<2048, 256, 0, stream>>>(anchor, sample, Abf, s_norm);

    gemm_bf16<<<NTRI, 256, 0, stream>>>(Abf, sim);

    topk_kernel<<<N / 4, 256, 0, stream>>>(sim, pos_idx, neg_idx, out);

    loss_kernel<<<LOSS_BLOCKS, 256, 0, stream>>>(s_norm, pos_idx, neg_idx, out);
}

// Round 10
// 94.761 us; speedup vs baseline: 1.5385x; 1.0327x over previous
//
#include <hip/hip_runtime.h>
#include <math.h>

#define N 4096
#define D 512
#define KPOS 5
#define KNEG 10
#define NB 32                      // 4096/128 block-rows
#define NTRI (NB * (NB + 1) / 2)   // 528 upper-triangle blocks

typedef short s16x8 __attribute__((ext_vector_type(8)));
typedef unsigned short u16x8 __attribute__((ext_vector_type(8)));
typedef float f32x4 __attribute__((ext_vector_type(4)));

__device__ __forceinline__ unsigned short f2bf(float x) {
    unsigned u = __float_as_uint(x);
    unsigned r = (u + 0x7FFFu + ((u >> 16) & 1u)) >> 16;   // RNE
    return (unsigned short)r;
}
__device__ __forceinline__ float bf2f(unsigned short b) {
    return __uint_as_float(((unsigned)b) << 16);
}
__device__ __forceinline__ unsigned umax_(unsigned a, unsigned b) { return a > b ? a : b; }
__device__ __forceinline__ unsigned umin_(unsigned a, unsigned b) { return a < b ? a : b; }

// ---------------------------------------------------------------------------
// Kernel 1: normalize. anchor rows (eps 1e-8) -> bf16 A (for MFMA GEMM).
// sample rows (eps 1e-12) -> bf16 s_norm (for the loss kernel).
// ---------------------------------------------------------------------------
__global__ __launch_bounds__(256) void norm_kernel(const float* __restrict__ anchor,
                                                   const float* __restrict__ sample,
                                                   unsigned short* __restrict__ Abf,
                                                   unsigned short* __restrict__ s_norm) {
    const int wave = threadIdx.x >> 6, lane = threadIdx.x & 63;
    const int row = blockIdx.x * 4 + wave;
    const bool is_anchor = row < N;
    const float* in = is_anchor ? anchor + (size_t)row * D
                                : sample + (size_t)(row - N) * D;
    const float eps = is_anchor ? 1e-8f : 1e-12f;

    float v[8];
    float ss = 0.f;
#pragma unroll
    for (int e = 0; e < 8; ++e) {
        v[e] = in[lane + 64 * e];
        ss = fmaf(v[e], v[e], ss);
    }
#pragma unroll
    for (int off = 32; off > 0; off >>= 1) ss += __shfl_xor(ss, off);
    const float denom = fmaxf(sqrtf(ss), eps);

    unsigned short* out = is_anchor ? Abf + (size_t)row * D
                                    : s_norm + (size_t)(row - N) * D;
#pragma unroll
    for (int e = 0; e < 8; ++e) out[lane + 64 * e] = f2bf(v[e] / denom);
}

// ---------------------------------------------------------------------------
// Kernel 2: sim = A@A^T, bf16 MFMA, K = 512. Upper-triangle compact grid
// (528 blocks) with T1 bijective XCD chunk swizzle. 128x128 tile, BK=64,
// double-buffered LDS, prefetch-before-compute, T2 XOR swizzle via
// pre-swizzled global source. bf16 output, off-diagonal mirror writes.
// ---------------------------------------------------------------------------
#define TILE (128 * 64)

__device__ __forceinline__ void stage_tile(const unsigned short* __restrict__ A,
                                           unsigned short* As, unsigned short* Bs,
                                           int rowA, int rowB, int kl, int t) {
#pragma unroll
    for (int i = 0; i < 4; ++i) {
        const int c = i * 256 + t;                 // 16B chunk id 0..1023
        const int r = c >> 3;                      // tile row 0..127
        const int ke = ((c & 7) ^ (r & 7)) * 8;    // swizzled k-element offset
        __builtin_amdgcn_global_load_lds(
            (const __attribute__((address_space(1))) void*)(A + (size_t)(rowA + r) * D + kl + ke),
            (__attribute__((address_space(3))) void*)(As + c * 8), 16, 0, 0);
    }
#pragma unroll
    for (int i = 0; i < 4; ++i) {
        const int c = i * 256 + t;
        const int r = c >> 3;
        const int ke = ((c & 7) ^ (r & 7)) * 8;
        __builtin_amdgcn_global_load_lds(
            (const __attribute__((address_space(1))) void*)(A + (size_t)(rowB + r) * D + kl + ke),
            (__attribute__((address_space(3))) void*)(Bs + c * 8), 16, 0, 0);
    }
}

__global__ __launch_bounds__(256) void gemm_bf16(const unsigned short* __restrict__ Abf,
                                                 unsigned short* __restrict__ C) {
    // T1: XCD chunk swizzle (bijective since NTRI % 8 == 0).
    const int q = (blockIdx.x % 8) * (NTRI / 8) + blockIdx.x / 8;
    // triangular decode: q -> (bi, bj), bi<=bj. S(i) = i*(2*NB+1-i)/2.
    int bi = (int)((2 * NB + 1 - sqrtf((float)((2 * NB + 1) * (2 * NB + 1) - 8 * q))) * 0.5f);
    while (bi * (2 * NB + 1 - bi) / 2 > q) --bi;
    while ((bi + 1) * (2 * NB + 1 - (bi + 1)) / 2 <= q) ++bi;
    const int bj = bi + (q - bi * (2 * NB + 1 - bi) / 2);

    __shared__ __align__(16) unsigned short As[2 * TILE];   // 2 x 16 KiB
    __shared__ __align__(16) unsigned short Bs[2 * TILE];   // 2 x 16 KiB

    const int t = threadIdx.x;
    const int l = t & 63;
    const int w = t >> 6;
    const int wr = w >> 1, wc = w & 1;
    const int rowA = bi * 128;
    const int rowB = bj * 128;
    const int lrow = l & 15, lgrp = l >> 4;

    f32x4 acc[4][4];
#pragma unroll
    for (int m = 0; m < 4; ++m)
#pragma unroll
        for (int n = 0; n < 4; ++n) acc[m][n] = (f32x4){0.f, 0.f, 0.f, 0.f};

    // prologue: stage k-step 0 into buffer 0
    stage_tile(Abf, As, Bs, rowA, rowB, 0, t);
    __syncthreads();   // drains vmcnt (compiler emits s_waitcnt before s_barrier)

    for (int kc = 0; kc < 8; ++kc) {
        const int cur = kc & 1;
        if (kc < 7)
            stage_tile(Abf, As + (cur ^ 1) * TILE, Bs + (cur ^ 1) * TILE,
                       rowA, rowB, (kc + 1) * 64, t);

        const char* AsB = (const char*)(As + cur * TILE);
        const char* BsB = (const char*)(Bs + cur * TILE);
#pragma unroll
        for (int kk = 0; kk < 2; ++kk) {
            s16x8 af[4], bfr[4];
#pragma unroll
            for (int m = 0; m < 4; ++m) {
                const int row = wr * 64 + m * 16 + lrow;
                af[m] = *(const s16x8*)(AsB + row * 128 + (((kk * 4 + lgrp) ^ (row & 7)) * 16));
            }
#pragma unroll
            for (int n = 0; n < 4; ++n) {
                const int row = wc * 64 + n * 16 + lrow;
                bfr[n] = *(const s16x8*)(BsB + row * 128 + (((kk * 4 + lgrp) ^ (row & 7)) * 16));
            }
#pragma unroll
            for (int m = 0; m < 4; ++m)
#pragma unroll
                for (int n = 0; n < 4; ++n)
                    acc[m][n] = __builtin_amdgcn_mfma_f32_16x16x32_bf16(af[m], bfr[n], acc[m][n], 0, 0, 0);
        }
        // drains this iter's prefetch and fences prev-buffer reuse.
        __syncthreads();
    }

    // C/D layout: col = lane&15, row = (lane>>4)*4 + j ; store bf16.
#pragma unroll
    for (int m = 0; m < 4; ++m) {
#pragma unroll
        for (int n = 0; n < 4; ++n) {
            const int col = rowB + wc * 64 + n * 16 + lrow;
            const int row0 = rowA + wr * 64 + m * 16 + lgrp * 4;
#pragma unroll
            for (int j = 0; j < 4; ++j)
                C[(size_t)(row0 + j) * N + col] = f2bf(acc[m][n][j]);
        }
    }
    if (bi != bj) {
        // mirror block: C[col][row0..row0+3] — 4 consecutive bf16 = 8B store.
#pragma unroll
        for (int m = 0; m < 4; ++m) {
#pragma unroll
            for (int n = 0; n < 4; ++n) {
                const int col = rowB + wc * 64 + n * 16 + lrow;
                const int row0 = rowA + wr * 64 + m * 16 + lgrp * 4;
                ushort4 pk;
                pk.x = f2bf(acc[m][n][0]);
                pk.y = f2bf(acc[m][n][1]);
                pk.z = f2bf(acc[m][n][2]);
                pk.w = f2bf(acc[m][n][3]);
                *(ushort4*)&C[(size_t)col * N + row0] = pk;
            }
        }
    }
}

// ---------------------------------------------------------------------------
// Kernel 3: wave-per-row top-5 / bottom-10 over bf16 sim, branchless packed
// u32 keys. Block 0 thread 0 zeroes the loss accumulator.
// ---------------------------------------------------------------------------
__global__ __launch_bounds__(256) void topk_kernel(const unsigned short* __restrict__ sim,
                                                   int* __restrict__ pos_idx,
                                                   int* __restrict__ neg_idx,
                                                   float* __restrict__ out) {
    if (blockIdx.x == 0 && threadIdx.x == 0) *out = 0.f;
    const int w = threadIdx.x >> 6, l = threadIdx.x & 63;
    const int row = blockIdx.x * 4 + w;
    const unsigned short* s = sim + (size_t)row * N;

    unsigned tk[KPOS], bk[KNEG];
#pragma unroll
    for (int q = 0; q < KPOS; ++q) tk[q] = 0u;
#pragma unroll
    for (int q = 0; q < KNEG; ++q) bk[q] = 0xFFFFFFFFu;

    for (int e = 0; e < 8; ++e) {
        const int base = 8 * (l + 64 * e);
        const u16x8 v8 = *(const u16x8*)&s[base];
#pragma unroll
        for (int j = 0; j < 8; ++j) {
            unsigned u = ((unsigned)v8[j]) << 16;
            u ^= ((unsigned)((int)u >> 31)) | 0x80000000u;   // monotone map
            const unsigned kv = u & 0xFFFF0000u;
            const int idx = base + j;

            unsigned c = kv | (unsigned)(4095 - idx);        // top key
#pragma unroll
            for (int q = 0; q < KPOS - 1; ++q) {
                const unsigned x = umax_(tk[q], c);
                c = umin_(tk[q], c);
                tk[q] = x;
            }
            tk[KPOS - 1] = umax_(tk[KPOS - 1], c);

            c = kv | (unsigned)idx;                          // bot key
#pragma unroll
            for (int q = 0; q < KNEG - 1; ++q) {
                const unsigned x = umin_(bk[q], c);
                c = umax_(bk[q], c);
                bk[q] = x;
            }
            bk[KNEG - 1] = umax_(bk[KNEG - 1], c);
        }
    }

    // ---- merge top-5 across the wave ----
    for (int it = 0; it < KPOS; ++it) {
        unsigned m = tk[0];
#pragma unroll
        for (int off = 32; off > 0; off >>= 1) m = umax_(m, (unsigned)__shfl_xor((int)m, off));
        if (l == 0) pos_idx[row * KPOS + it] = 4095 - (int)(m & 0xFFFu);
        if (tk[0] == m) {   // unique key -> exactly one lane pops
#pragma unroll
            for (int q = 0; q < KPOS - 1; ++q) tk[q] = tk[q + 1];
            tk[KPOS - 1] = 0u;
        }
    }

    // ---- merge bottom-10 across the wave ----
    for (int it = 0; it < KNEG; ++it) {
        unsigned m = bk[0];
#pragma unroll
        for (int off = 32; off > 0; off >>= 1) m = umin_(m, (unsigned)__shfl_xor((int)m, off));
        if (l == 0) neg_idx[row * KNEG + it] = (int)(m & 0xFFFu);
        if (bk[0] == m) {
#pragma unroll
            for (int q = 0; q < KNEG - 1; ++q) bk[q] = bk[q + 1];
            bk[KNEG - 1] = 0xFFFFFFFFu;
        }
    }
}

// ---------------------------------------------------------------------------
// Kernel 4: InfoNCE loss, one wave per anchor ia (j = ia*5 + p).
// The 10 negative rows are shared by all 5 p's: load once into registers
// (packed bf16), loop p over {query, pos}. 1024 blocks x 4 waves = 4096
// waves -> 4 blocks/CU (16 waves/CU) hides gather latency. One atomic/block.
// ---------------------------------------------------------------------------
__global__ __launch_bounds__(256) void loss_kernel(const unsigned short* __restrict__ s_norm,
                                                   const int* __restrict__ pos_idx,
                                                   const int* __restrict__ neg_idx,
                                                   float* __restrict__ out) {
    __shared__ float wsum[4];
    const int wave = threadIdx.x >> 6, lane = threadIdx.x & 63;
    const int ia = blockIdx.x * 4 + wave;   // 0..4095

    // load the 10 shared negative rows (keep packed bf16: 40 VGPRs)
    u16x8 nr[KNEG];
#pragma unroll
    for (int k = 0; k < KNEG; ++k)
        nr[k] = *(const u16x8*)(s_norm + (size_t)neg_idx[ia * KNEG + k] * D + lane * 8);

    float lsum = 0.f;
#pragma unroll
    for (int p = 0; p < KPOS; ++p) {
        const int j = ia * KPOS + p;
        const int iq = j & (N - 1);

        const u16x8 qr = *(const u16x8*)(s_norm + (size_t)iq * D + lane * 8);
        float qv[8];
#pragma unroll
        for (int e = 0; e < 8; ++e) qv[e] = bf2f(qr[e]);

        const int pi = pos_idx[ia * KPOS + p];
        const u16x8 pr = *(const u16x8*)(s_norm + (size_t)pi * D + lane * 8);
        float accp = 0.f;
#pragma unroll
        for (int e = 0; e < 8; ++e) accp = fmaf(qv[e], bf2f(pr[e]), accp);

        float accn[KNEG];
#pragma unroll
        for (int k = 0; k < KNEG; ++k) {
            float a = 0.f;
#pragma unroll
            for (int e = 0; e < 8; ++e) a = fmaf(qv[e], bf2f(nr[k][e]), a);
            accn[k] = a;
        }

#pragma unroll
        for (int off = 32; off > 0; off >>= 1) {
            accp += __shfl_xor(accp, off);
#pragma unroll
            for (int k = 0; k < KNEG; ++k) accn[k] += __shfl_xor(accn[k], off);
        }

        const float l0 = accp * 10.f;
        float m = l0;
#pragma unroll
        for (int k = 0; k < KNEG; ++k) m = fmaxf(m, accn[k] * 10.f);
        float ssum = expf(l0 - m);
#pragma unroll
        for (int k = 0; k < KNEG; ++k) ssum += expf(accn[k] * 10.f - m);
        lsum += logf(ssum) + m - l0;
    }

    if (lane == 0) wsum[wave] = lsum;
    __syncthreads();
    if (threadIdx.x == 0) {
        const float total = wsum[0] + wsum[1] + wsum[2] + wsum[3];
        atomicAdd(out, total * (1.0f / (float)(N * KPOS)));
    }
}

// ---------------------------------------------------------------------------
extern "C" void kernel_launch(void* const* d_in, const int* in_sizes, int n_in,
                              void* d_out, int out_size, void* d_ws, size_t ws_size,
                              hipStream_t stream) {
    const float* anchor = (const float*)d_in[0];
    const float* sample = (const float*)d_in[1];
    float* out = (float*)d_out;

    char* ws = (char*)d_ws;
    unsigned short* Abf    = (unsigned short*)ws;                               // 4 MiB
    unsigned short* s_norm = (unsigned short*)(ws + (size_t)4 * 1024 * 1024);   // 4 MiB
    unsigned short* sim    = (unsigned short*)(ws + (size_t)8 * 1024 * 1024);   // 32 MiB
    int* pos_idx  = (int*)(ws + (size_t)40 * 1024 * 1024);
    int* neg_idx  = (int*)(ws + (size_t)40 * 1024 * 1024 + (size_t)N * KPOS * sizeof(int));

    norm_kernel<<<2048, 256, 0, stream>>>(anchor, sample, Abf, s_norm);

    gemm_bf16<<<NTRI, 256, 0, stream>>>(Abf, sim);

    topk_kernel<<<N / 4, 256, 0, stream>>>(sim, pos_idx, neg_idx, out);

    loss_kernel<<<N / 4, 256, 0, stream>>>(s_norm, pos_idx, neg_idx, out);
}

// Round 11
// 76.005 us; speedup vs baseline: 1.9182x; 1.2468x over previous
//
#include <hip/hip_runtime.h>
#include <math.h>

#define N 4096
#define D 512
#define KPOS 5
#define KNEG 10
#define NB 32                      // 4096/128 block-rows
#define NTRI (NB * (NB + 1) / 2)   // 528 upper-triangle blocks

typedef short s16x8 __attribute__((ext_vector_type(8)));
typedef unsigned short u16x8 __attribute__((ext_vector_type(8)));
typedef float f32x4 __attribute__((ext_vector_type(4)));

__device__ __forceinline__ unsigned short f2bf(float x) {
    unsigned u = __float_as_uint(x);
    unsigned r = (u + 0x7FFFu + ((u >> 16) & 1u)) >> 16;   // RNE
    return (unsigned short)r;
}
__device__ __forceinline__ float bf2f(unsigned short b) {
    return __uint_as_float(((unsigned)b) << 16);
}
__device__ __forceinline__ unsigned umax_(unsigned a, unsigned b) { return a > b ? a : b; }
__device__ __forceinline__ unsigned umin_(unsigned a, unsigned b) { return a < b ? a : b; }

// ---------------------------------------------------------------------------
// Kernel 1: normalize. anchor rows (eps 1e-8) -> bf16 A (for MFMA GEMM).
// sample rows (eps 1e-12) -> bf16 s_norm (for the loss kernel).
// ---------------------------------------------------------------------------
__global__ __launch_bounds__(256) void norm_kernel(const float* __restrict__ anchor,
                                                   const float* __restrict__ sample,
                                                   unsigned short* __restrict__ Abf,
                                                   unsigned short* __restrict__ s_norm) {
    const int wave = threadIdx.x >> 6, lane = threadIdx.x & 63;
    const int row = blockIdx.x * 4 + wave;
    const bool is_anchor = row < N;
    const float* in = is_anchor ? anchor + (size_t)row * D
                                : sample + (size_t)(row - N) * D;
    const float eps = is_anchor ? 1e-8f : 1e-12f;

    float v[8];
    float ss = 0.f;
#pragma unroll
    for (int e = 0; e < 8; ++e) {
        v[e] = in[lane + 64 * e];
        ss = fmaf(v[e], v[e], ss);
    }
#pragma unroll
    for (int off = 32; off > 0; off >>= 1) ss += __shfl_xor(ss, off);
    const float denom = fmaxf(sqrtf(ss), eps);

    unsigned short* out = is_anchor ? Abf + (size_t)row * D
                                    : s_norm + (size_t)(row - N) * D;
#pragma unroll
    for (int e = 0; e < 8; ++e) out[lane + 64 * e] = f2bf(v[e] / denom);
}

// ---------------------------------------------------------------------------
// Kernel 2: sim = A@A^T, bf16 MFMA, K = 512. Upper-triangle compact grid
// (528 blocks) with T1 bijective XCD chunk swizzle. 128x128 tile, BK=64,
// double-buffered LDS, prefetch-before-compute, T2 XOR swizzle via
// pre-swizzled global source. bf16 output, off-diagonal mirror writes.
// ---------------------------------------------------------------------------
#define TILE (128 * 64)

__device__ __forceinline__ void stage_tile(const unsigned short* __restrict__ A,
                                           unsigned short* As, unsigned short* Bs,
                                           int rowA, int rowB, int kl, int t) {
#pragma unroll
    for (int i = 0; i < 4; ++i) {
        const int c = i * 256 + t;                 // 16B chunk id 0..1023
        const int r = c >> 3;                      // tile row 0..127
        const int ke = ((c & 7) ^ (r & 7)) * 8;    // swizzled k-element offset
        __builtin_amdgcn_global_load_lds(
            (const __attribute__((address_space(1))) void*)(A + (size_t)(rowA + r) * D + kl + ke),
            (__attribute__((address_space(3))) void*)(As + c * 8), 16, 0, 0);
    }
#pragma unroll
    for (int i = 0; i < 4; ++i) {
        const int c = i * 256 + t;
        const int r = c >> 3;
        const int ke = ((c & 7) ^ (r & 7)) * 8;
        __builtin_amdgcn_global_load_lds(
            (const __attribute__((address_space(1))) void*)(A + (size_t)(rowB + r) * D + kl + ke),
            (__attribute__((address_space(3))) void*)(Bs + c * 8), 16, 0, 0);
    }
}

__global__ __launch_bounds__(256) void gemm_bf16(const unsigned short* __restrict__ Abf,
                                                 unsigned short* __restrict__ C) {
    // T1: XCD chunk swizzle (bijective since NTRI % 8 == 0).
    const int q = (blockIdx.x % 8) * (NTRI / 8) + blockIdx.x / 8;
    // triangular decode: q -> (bi, bj), bi<=bj. S(i) = i*(2*NB+1-i)/2.
    int bi = (int)((2 * NB + 1 - sqrtf((float)((2 * NB + 1) * (2 * NB + 1) - 8 * q))) * 0.5f);
    while (bi * (2 * NB + 1 - bi) / 2 > q) --bi;
    while ((bi + 1) * (2 * NB + 1 - (bi + 1)) / 2 <= q) ++bi;
    const int bj = bi + (q - bi * (2 * NB + 1 - bi) / 2);

    __shared__ __align__(16) unsigned short As[2 * TILE];   // 2 x 16 KiB
    __shared__ __align__(16) unsigned short Bs[2 * TILE];   // 2 x 16 KiB

    const int t = threadIdx.x;
    const int l = t & 63;
    const int w = t >> 6;
    const int wr = w >> 1, wc = w & 1;
    const int rowA = bi * 128;
    const int rowB = bj * 128;
    const int lrow = l & 15, lgrp = l >> 4;

    f32x4 acc[4][4];
#pragma unroll
    for (int m = 0; m < 4; ++m)
#pragma unroll
        for (int n = 0; n < 4; ++n) acc[m][n] = (f32x4){0.f, 0.f, 0.f, 0.f};

    // prologue: stage k-step 0 into buffer 0
    stage_tile(Abf, As, Bs, rowA, rowB, 0, t);
    __syncthreads();   // drains vmcnt (compiler emits s_waitcnt before s_barrier)

    for (int kc = 0; kc < 8; ++kc) {
        const int cur = kc & 1;
        if (kc < 7)
            stage_tile(Abf, As + (cur ^ 1) * TILE, Bs + (cur ^ 1) * TILE,
                       rowA, rowB, (kc + 1) * 64, t);

        const char* AsB = (const char*)(As + cur * TILE);
        const char* BsB = (const char*)(Bs + cur * TILE);
#pragma unroll
        for (int kk = 0; kk < 2; ++kk) {
            s16x8 af[4], bfr[4];
#pragma unroll
            for (int m = 0; m < 4; ++m) {
                const int row = wr * 64 + m * 16 + lrow;
                af[m] = *(const s16x8*)(AsB + row * 128 + (((kk * 4 + lgrp) ^ (row & 7)) * 16));
            }
#pragma unroll
            for (int n = 0; n < 4; ++n) {
                const int row = wc * 64 + n * 16 + lrow;
                bfr[n] = *(const s16x8*)(BsB + row * 128 + (((kk * 4 + lgrp) ^ (row & 7)) * 16));
            }
#pragma unroll
            for (int m = 0; m < 4; ++m)
#pragma unroll
                for (int n = 0; n < 4; ++n)
                    acc[m][n] = __builtin_amdgcn_mfma_f32_16x16x32_bf16(af[m], bfr[n], acc[m][n], 0, 0, 0);
        }
        // drains this iter's prefetch and fences prev-buffer reuse.
        __syncthreads();
    }

    // C/D layout: col = lane&15, row = (lane>>4)*4 + j ; store bf16.
#pragma unroll
    for (int m = 0; m < 4; ++m) {
#pragma unroll
        for (int n = 0; n < 4; ++n) {
            const int col = rowB + wc * 64 + n * 16 + lrow;
            const int row0 = rowA + wr * 64 + m * 16 + lgrp * 4;
#pragma unroll
            for (int j = 0; j < 4; ++j)
                C[(size_t)(row0 + j) * N + col] = f2bf(acc[m][n][j]);
        }
    }
    if (bi != bj) {
        // mirror block: C[col][row0..row0+3] — 4 consecutive bf16 = 8B store.
#pragma unroll
        for (int m = 0; m < 4; ++m) {
#pragma unroll
            for (int n = 0; n < 4; ++n) {
                const int col = rowB + wc * 64 + n * 16 + lrow;
                const int row0 = rowA + wr * 64 + m * 16 + lgrp * 4;
                ushort4 pk;
                pk.x = f2bf(acc[m][n][0]);
                pk.y = f2bf(acc[m][n][1]);
                pk.z = f2bf(acc[m][n][2]);
                pk.w = f2bf(acc[m][n][3]);
                *(ushort4*)&C[(size_t)col * N + row0] = pk;
            }
        }
    }
}

// ---------------------------------------------------------------------------
// Kernel 3: wave-per-row top-5 / bottom-10 over bf16 sim, branchless packed
// u32 keys (monotone bf16 | idx; idx complemented for top -> jax stable order).
// ---------------------------------------------------------------------------
__global__ __launch_bounds__(256) void topk_kernel(const unsigned short* __restrict__ sim,
                                                   int* __restrict__ pos_idx,
                                                   int* __restrict__ neg_idx) {
    const int w = threadIdx.x >> 6, l = threadIdx.x & 63;
    const int row = blockIdx.x * 4 + w;
    const unsigned short* s = sim + (size_t)row * N;

    unsigned tk[KPOS], bk[KNEG];
#pragma unroll
    for (int q = 0; q < KPOS; ++q) tk[q] = 0u;
#pragma unroll
    for (int q = 0; q < KNEG; ++q) bk[q] = 0xFFFFFFFFu;

    for (int e = 0; e < 8; ++e) {
        const int base = 8 * (l + 64 * e);
        const u16x8 v8 = *(const u16x8*)&s[base];
#pragma unroll
        for (int j = 0; j < 8; ++j) {
            unsigned u = ((unsigned)v8[j]) << 16;
            u ^= ((unsigned)((int)u >> 31)) | 0x80000000u;   // monotone map
            const unsigned kv = u & 0xFFFF0000u;
            const int idx = base + j;

            unsigned c = kv | (unsigned)(4095 - idx);        // top key
#pragma unroll
            for (int q = 0; q < KPOS - 1; ++q) {
                const unsigned x = umax_(tk[q], c);
                c = umin_(tk[q], c);
                tk[q] = x;
            }
            tk[KPOS - 1] = umax_(tk[KPOS - 1], c);

            c = kv | (unsigned)idx;                          // bot key
#pragma unroll
            for (int q = 0; q < KNEG - 1; ++q) {
                const unsigned x = umin_(bk[q], c);
                c = umax_(bk[q], c);
                bk[q] = x;
            }
            bk[KNEG - 1] = umax_(bk[KNEG - 1], c);
        }
    }

    // ---- merge top-5 across the wave ----
    for (int it = 0; it < KPOS; ++it) {
        unsigned m = tk[0];
#pragma unroll
        for (int off = 32; off > 0; off >>= 1) m = umax_(m, (unsigned)__shfl_xor((int)m, off));
        if (l == 0) pos_idx[row * KPOS + it] = 4095 - (int)(m & 0xFFFu);
        if (tk[0] == m) {   // unique key -> exactly one lane pops
#pragma unroll
            for (int q = 0; q < KPOS - 1; ++q) tk[q] = tk[q + 1];
            tk[KPOS - 1] = 0u;
        }
    }

    // ---- merge bottom-10 across the wave ----
    for (int it = 0; it < KNEG; ++it) {
        unsigned m = bk[0];
#pragma unroll
        for (int off = 32; off > 0; off >>= 1) m = umin_(m, (unsigned)__shfl_xor((int)m, off));
        if (l == 0) neg_idx[row * KNEG + it] = (int)(m & 0xFFFu);
        if (bk[0] == m) {
#pragma unroll
            for (int q = 0; q < KNEG - 1; ++q) bk[q] = bk[q + 1];
            bk[KNEG - 1] = 0xFFFFFFFFu;
        }
    }
}

// ---------------------------------------------------------------------------
// Kernel 4: InfoNCE loss, MFMA version. One wave per anchor ia.
// A-operand rows (l&15): 0..4 = query rows (ia*5+p mod N), rest dup row 0.
// B-operand rows (l&15): 0..4 = pos rows, 5..14 = neg rows, 15 dup.
// 32 independent 16B fragment loads up-front (deep MLP), 16 chained MFMAs;
// C[p][c] = q_p . other_c with col = lane&15, row = (lane>>4)*4 + j.
// Softmax per row via 16-lane-group shuffles; block partial -> partials[].
// ---------------------------------------------------------------------------
__global__ __launch_bounds__(256) void loss_kernel(const unsigned short* __restrict__ s_norm,
                                                   const int* __restrict__ pos_idx,
                                                   const int* __restrict__ neg_idx,
                                                   float* __restrict__ partials) {
    __shared__ float wsum[4];
    const int wave = threadIdx.x >> 6, lane = threadIdx.x & 63;
    const int ia = blockIdx.x * 4 + wave;   // 0..4095
    const int c = lane & 15;                // A-row / B-col selector
    const int g = lane >> 4;                // k-group

    const int qbase = ia * KPOS;
    const int rowA = (qbase + ((c < KPOS) ? c : 0)) & (N - 1);
    int rowB;
    if (c < KPOS)      rowB = pos_idx[qbase + c];
    else if (c < 15)   rowB = neg_idx[ia * KNEG + (c - KPOS)];
    else               rowB = pos_idx[qbase];

    const unsigned short* pA = s_norm + (size_t)rowA * D + g * 8;
    const unsigned short* pB = s_norm + (size_t)rowB * D + g * 8;

    s16x8 a[16], b[16];
#pragma unroll
    for (int kk = 0; kk < 16; ++kk) {
        a[kk] = *(const s16x8*)(pA + kk * 32);
        b[kk] = *(const s16x8*)(pB + kk * 32);
    }
    f32x4 acc = (f32x4){0.f, 0.f, 0.f, 0.f};
#pragma unroll
    for (int kk = 0; kk < 16; ++kk)
        acc = __builtin_amdgcn_mfma_f32_16x16x32_bf16(a[kk], b[kk], acc, 0, 0, 0);

    // per-row online softmax across the 16-lane group
    float lsum = 0.f;
#pragma unroll
    for (int j = 0; j < 4; ++j) {
        const int p = g * 4 + j;                 // output row this reg belongs to
        const float logit = acc[j] * 10.f;
        const bool isneg = (c >= KPOS) && (c < 15);
        const bool ispos = (c == p);
        float x = (ispos || isneg) ? logit : -__builtin_inff();
        float m = x;
#pragma unroll
        for (int off = 1; off < 16; off <<= 1) m = fmaxf(m, __shfl_xor(m, off));
        float e = (ispos || isneg) ? expf(logit - m) : 0.f;
        float s = e;
#pragma unroll
        for (int off = 1; off < 16; off <<= 1) s += __shfl_xor(s, off);
        float l0 = ispos ? logit : 0.f;
#pragma unroll
        for (int off = 1; off < 16; off <<= 1) l0 += __shfl_xor(l0, off);
        if (p < KPOS && ispos) lsum += logf(s) + m - l0;   // one lane per row
    }

#pragma unroll
    for (int off = 32; off > 0; off >>= 1) lsum += __shfl_xor(lsum, off);
    if (lane == 0) wsum[wave] = lsum;
    __syncthreads();
    if (threadIdx.x == 0)
        partials[blockIdx.x] = wsum[0] + wsum[1] + wsum[2] + wsum[3];
}

// ---------------------------------------------------------------------------
// Kernel 5: final deterministic reduce of 1024 block partials.
// ---------------------------------------------------------------------------
__global__ __launch_bounds__(256) void reduce_kernel(const float* __restrict__ partials,
                                                     float* __restrict__ out) {
    __shared__ float wsum[4];
    const int wave = threadIdx.x >> 6, lane = threadIdx.x & 63;
    float s = partials[threadIdx.x] + partials[threadIdx.x + 256] +
              partials[threadIdx.x + 512] + partials[threadIdx.x + 768];
#pragma unroll
    for (int off = 32; off > 0; off >>= 1) s += __shfl_xor(s, off);
    if (lane == 0) wsum[wave] = s;
    __syncthreads();
    if (threadIdx.x == 0)
        *out = (wsum[0] + wsum[1] + wsum[2] + wsum[3]) * (1.0f / (float)(N * KPOS));
}

// ---------------------------------------------------------------------------
extern "C" void kernel_launch(void* const* d_in, const int* in_sizes, int n_in,
                              void* d_out, int out_size, void* d_ws, size_t ws_size,
                              hipStream_t stream) {
    const float* anchor = (const float*)d_in[0];
    const float* sample = (const float*)d_in[1];
    float* out = (float*)d_out;

    char* ws = (char*)d_ws;
    unsigned short* Abf    = (unsigned short*)ws;                               // 4 MiB
    unsigned short* s_norm = (unsigned short*)(ws + (size_t)4 * 1024 * 1024);   // 4 MiB
    unsigned short* sim    = (unsigned short*)(ws + (size_t)8 * 1024 * 1024);   // 32 MiB
    int* pos_idx  = (int*)(ws + (size_t)40 * 1024 * 1024);
    int* neg_idx  = (int*)(ws + (size_t)40 * 1024 * 1024 + (size_t)N * KPOS * sizeof(int));
    float* partials = (float*)(ws + (size_t)41 * 1024 * 1024);                  // 4 KiB

    norm_kernel<<<2048, 256, 0, stream>>>(anchor, sample, Abf, s_norm);

    gemm_bf16<<<NTRI, 256, 0, stream>>>(Abf, sim);

    topk_kernel<<<N / 4, 256, 0, stream>>>(sim, pos_idx, neg_idx);

    loss_kernel<<<N / 4, 256, 0, stream>>>(s_norm, pos_idx, neg_idx, partials);

    reduce_kernel<<<1, 256, 0, stream>>>(partials, out);
}

// Round 12
// 62.507 us; speedup vs baseline: 2.3324x; 1.2159x over previous
//
#include <hip/hip_runtime.h>
#include <math.h>

#define N 4096
#define D 512
#define KPOS 5
#define KNEG 10
#define NB 32                      // 4096/128 block-rows
#define NPAIR (NB * (NB - 1) / 2)  // 496 strict upper pairs
#define NJOB 1024                  // 992 off-diag half-jobs + 32 diag half-jobs

typedef short s16x8 __attribute__((ext_vector_type(8)));
typedef unsigned short u16x8 __attribute__((ext_vector_type(8)));
typedef float f32x4 __attribute__((ext_vector_type(4)));

__device__ __forceinline__ unsigned short f2bf(float x) {
    unsigned u = __float_as_uint(x);
    unsigned r = (u + 0x7FFFu + ((u >> 16) & 1u)) >> 16;   // RNE
    return (unsigned short)r;
}
__device__ __forceinline__ float bf2f(unsigned short b) {
    return __uint_as_float(((unsigned)b) << 16);
}
__device__ __forceinline__ unsigned umax_(unsigned a, unsigned b) { return a > b ? a : b; }
__device__ __forceinline__ unsigned umin_(unsigned a, unsigned b) { return a < b ? a : b; }

// ---------------------------------------------------------------------------
// Kernel 1: normalize. anchor rows (eps 1e-8) -> bf16 A; sample rows
// (eps 1e-12) -> bf16 s_norm.
// ---------------------------------------------------------------------------
__global__ __launch_bounds__(256) void norm_kernel(const float* __restrict__ anchor,
                                                   const float* __restrict__ sample,
                                                   unsigned short* __restrict__ Abf,
                                                   unsigned short* __restrict__ s_norm) {
    const int wave = threadIdx.x >> 6, lane = threadIdx.x & 63;
    const int row = blockIdx.x * 4 + wave;
    const bool is_anchor = row < N;
    const float* in = is_anchor ? anchor + (size_t)row * D
                                : sample + (size_t)(row - N) * D;
    const float eps = is_anchor ? 1e-8f : 1e-12f;

    float v[8];
    float ss = 0.f;
#pragma unroll
    for (int e = 0; e < 8; ++e) {
        v[e] = in[lane + 64 * e];
        ss = fmaf(v[e], v[e], ss);
    }
#pragma unroll
    for (int off = 32; off > 0; off >>= 1) ss += __shfl_xor(ss, off);
    const float denom = fmaxf(sqrtf(ss), eps);

    unsigned short* out = is_anchor ? Abf + (size_t)row * D
                                    : s_norm + (size_t)(row - N) * D;
#pragma unroll
    for (int e = 0; e < 8; ++e) out[lane + 64 * e] = f2bf(v[e] / denom);
}

// ---------------------------------------------------------------------------
// Kernel 2: sim = A@A^T, bf16 MFMA, K = 512. 1024 balanced half-jobs
// (128 rows x 64 cols): off-diag pair (bi<bj) x 2 col-halves -> 992 jobs,
// diag block x 2 col-halves -> 32 jobs. Exactly 4 jobs/CU -> no whole-job
// tail. LDS 48 KiB dbuf (A 2x16K, B 2x8K) -> 3 blocks/CU resident.
// Prefetch-before-compute dbuf, T2 XOR swizzle via pre-swizzled source,
// T1 XCD chunk swizzle. Off-diag jobs write normal + transposed mirror.
// ---------------------------------------------------------------------------
#define ATILE (128 * 64)
#define BTILE (64 * 64)

__device__ __forceinline__ void stage_ab(const unsigned short* __restrict__ A,
                                         unsigned short* As, unsigned short* Bs,
                                         int rowA, int colB, int kl, int t) {
#pragma unroll
    for (int i = 0; i < 4; ++i) {
        const int c = i * 256 + t;                 // 16B chunk id 0..1023
        const int r = c >> 3;                      // tile row 0..127
        const int ke = ((c & 7) ^ (r & 7)) * 8;    // swizzled k-element offset
        __builtin_amdgcn_global_load_lds(
            (const __attribute__((address_space(1))) void*)(A + (size_t)(rowA + r) * D + kl + ke),
            (__attribute__((address_space(3))) void*)(As + c * 8), 16, 0, 0);
    }
#pragma unroll
    for (int i = 0; i < 2; ++i) {
        const int c = i * 256 + t;                 // 0..511
        const int r = c >> 3;                      // B tile row 0..63
        const int ke = ((c & 7) ^ (r & 7)) * 8;
        __builtin_amdgcn_global_load_lds(
            (const __attribute__((address_space(1))) void*)(A + (size_t)(colB + r) * D + kl + ke),
            (__attribute__((address_space(3))) void*)(Bs + c * 8), 16, 0, 0);
    }
}

__global__ __launch_bounds__(256) void gemm_bf16(const unsigned short* __restrict__ Abf,
                                                 unsigned short* __restrict__ C) {
    // T1: XCD chunk swizzle (bijective, NJOB % 8 == 0).
    const int q = (blockIdx.x % 8) * (NJOB / 8) + blockIdx.x / 8;

    int bi, bj, h;
    if (q < 2 * NPAIR) {
        const int op = q >> 1;                 // strict pair index 0..495
        h = q & 1;
        // C(i) = 31i - i(i-1)/2 ; find bi with C(bi) <= op < C(bi+1)
        bi = (int)(31.5f - sqrtf(31.5f * 31.5f - 2.f * (float)op));
        while (31 * bi - bi * (bi - 1) / 2 > op) --bi;
        while (31 * (bi + 1) - (bi + 1) * bi / 2 <= op) ++bi;
        bj = bi + 1 + (op - (31 * bi - bi * (bi - 1) / 2));
    } else {
        const int d = q - 2 * NPAIR;           // 0..31
        bi = bj = d >> 1;
        h = d & 1;
    }

    __shared__ __align__(16) unsigned short As[2 * ATILE];   // 2 x 16 KiB
    __shared__ __align__(16) unsigned short Bs[2 * BTILE];   // 2 x 8 KiB

    const int t = threadIdx.x;
    const int l = t & 63;
    const int w = t >> 6;
    const int wr = w >> 1, wc = w & 1;         // wave tile: 64 rows x 32 cols
    const int rowA = bi * 128;
    const int colB = bj * 128 + h * 64;
    const int lrow = l & 15, lgrp = l >> 4;

    f32x4 acc[4][2];
#pragma unroll
    for (int m = 0; m < 4; ++m)
#pragma unroll
        for (int n = 0; n < 2; ++n) acc[m][n] = (f32x4){0.f, 0.f, 0.f, 0.f};

    stage_ab(Abf, As, Bs, rowA, colB, 0, t);
    __syncthreads();

    for (int kc = 0; kc < 8; ++kc) {
        const int cur = kc & 1;
        if (kc < 7)
            stage_ab(Abf, As + (cur ^ 1) * ATILE, Bs + (cur ^ 1) * BTILE,
                     rowA, colB, (kc + 1) * 64, t);

        const char* AsB = (const char*)(As + cur * ATILE);
        const char* BsB = (const char*)(Bs + cur * BTILE);
#pragma unroll
        for (int kk = 0; kk < 2; ++kk) {
            s16x8 af[4], bfr[2];
#pragma unroll
            for (int m = 0; m < 4; ++m) {
                const int row = wr * 64 + m * 16 + lrow;
                af[m] = *(const s16x8*)(AsB + row * 128 + (((kk * 4 + lgrp) ^ (row & 7)) * 16));
            }
#pragma unroll
            for (int n = 0; n < 2; ++n) {
                const int row = wc * 32 + n * 16 + lrow;   // B tile row 0..63
                bfr[n] = *(const s16x8*)(BsB + row * 128 + (((kk * 4 + lgrp) ^ (row & 7)) * 16));
            }
#pragma unroll
            for (int m = 0; m < 4; ++m)
#pragma unroll
                for (int n = 0; n < 2; ++n)
                    acc[m][n] = __builtin_amdgcn_mfma_f32_16x16x32_bf16(af[m], bfr[n], acc[m][n], 0, 0, 0);
        }
        __syncthreads();
    }

    // C/D layout: col = lane&15, row = (lane>>4)*4 + j ; store bf16.
#pragma unroll
    for (int m = 0; m < 4; ++m) {
#pragma unroll
        for (int n = 0; n < 2; ++n) {
            const int col = colB + wc * 32 + n * 16 + lrow;
            const int row0 = rowA + wr * 64 + m * 16 + lgrp * 4;
#pragma unroll
            for (int j = 0; j < 4; ++j)
                C[(size_t)(row0 + j) * N + col] = f2bf(acc[m][n][j]);
        }
    }
    if (bi != bj) {
        // mirror: C[col][row0..row0+3] — 4 consecutive bf16 = 8B store.
#pragma unroll
        for (int m = 0; m < 4; ++m) {
#pragma unroll
            for (int n = 0; n < 2; ++n) {
                const int col = colB + wc * 32 + n * 16 + lrow;
                const int row0 = rowA + wr * 64 + m * 16 + lgrp * 4;
                ushort4 pk;
                pk.x = f2bf(acc[m][n][0]);
                pk.y = f2bf(acc[m][n][1]);
                pk.z = f2bf(acc[m][n][2]);
                pk.w = f2bf(acc[m][n][3]);
                *(ushort4*)&C[(size_t)col * N + row0] = pk;
            }
        }
    }
}

// ---------------------------------------------------------------------------
// Kernel 3: FUSED topk + loss. One wave per anchor row ia.
// Phase A: branchless packed-key top-5 / bottom-10 over the bf16 sim row;
// winner indices captured into rowB via predicated select during the merge
// (no arrays -> no scratch, no global idx round-trip).
// Phase B: r11 MFMA loss: A rows = 5 query rows, B cols = 5 pos + 10 neg;
// 32 up-front 16B gathers, 16 chained MFMAs, 16-lane-group softmax.
// Block partial -> partials[]; reduce kernel finishes deterministically.
// ---------------------------------------------------------------------------
__global__ __launch_bounds__(256) void fused_topk_loss(const unsigned short* __restrict__ sim,
                                                       const unsigned short* __restrict__ s_norm,
                                                       float* __restrict__ partials) {
    __shared__ float wsum[4];
    const int wave = threadIdx.x >> 6, lane = threadIdx.x & 63;
    const int ia = blockIdx.x * 4 + wave;
    const unsigned short* s = sim + (size_t)ia * N;
    const int cc = lane & 15;               // loss column selector
    const int g = lane >> 4;                // loss k-group

    unsigned tk[KPOS], bk[KNEG];
#pragma unroll
    for (int qq = 0; qq < KPOS; ++qq) tk[qq] = 0u;
#pragma unroll
    for (int qq = 0; qq < KNEG; ++qq) bk[qq] = 0xFFFFFFFFu;

    for (int e = 0; e < 8; ++e) {
        const int base = 8 * (lane + 64 * e);
        const u16x8 v8 = *(const u16x8*)&s[base];
#pragma unroll
        for (int j = 0; j < 8; ++j) {
            unsigned u = ((unsigned)v8[j]) << 16;
            u ^= ((unsigned)((int)u >> 31)) | 0x80000000u;   // monotone map
            const unsigned kv = u & 0xFFFF0000u;
            const int idx = base + j;

            unsigned c = kv | (unsigned)(4095 - idx);        // top key
#pragma unroll
            for (int qq = 0; qq < KPOS - 1; ++qq) {
                const unsigned x = umax_(tk[qq], c);
                c = umin_(tk[qq], c);
                tk[qq] = x;
            }
            tk[KPOS - 1] = umax_(tk[KPOS - 1], c);

            c = kv | (unsigned)idx;                          // bot key
#pragma unroll
            for (int qq = 0; qq < KNEG - 1; ++qq) {
                const unsigned x = umin_(bk[qq], c);
                c = umax_(bk[qq], c);
                bk[qq] = x;
            }
            bk[KNEG - 1] = umax_(bk[KNEG - 1], c);
        }
    }

    int rowB = 0;                            // (cc==15 dummy stays 0)
    // ---- merge top-5 across the wave; capture pos indices ----
#pragma unroll
    for (int it = 0; it < KPOS; ++it) {
        unsigned m = tk[0];
#pragma unroll
        for (int off = 32; off > 0; off >>= 1) m = umax_(m, (unsigned)__shfl_xor((int)m, off));
        const int widx = 4095 - (int)(m & 0xFFFu);
        if (cc == it) rowB = widx;
        if (tk[0] == m) {
#pragma unroll
            for (int qq = 0; qq < KPOS - 1; ++qq) tk[qq] = tk[qq + 1];
            tk[KPOS - 1] = 0u;
        }
    }
    // ---- merge bottom-10 across the wave; capture neg indices ----
#pragma unroll
    for (int it = 0; it < KNEG; ++it) {
        unsigned m = bk[0];
#pragma unroll
        for (int off = 32; off > 0; off >>= 1) m = umin_(m, (unsigned)__shfl_xor((int)m, off));
        const int widx = (int)(m & 0xFFFu);
        if (cc == KPOS + it) rowB = widx;
        if (bk[0] == m) {
#pragma unroll
            for (int qq = 0; qq < KNEG - 1; ++qq) bk[qq] = bk[qq + 1];
            bk[KNEG - 1] = 0xFFFFFFFFu;
        }
    }

    // ---- loss: A rows = query rows (ia*5+p mod N), B cols = pos/neg ----
    const int rowA = (ia * KPOS + ((cc < KPOS) ? cc : 0)) & (N - 1);
    const unsigned short* pA = s_norm + (size_t)rowA * D + g * 8;
    const unsigned short* pB = s_norm + (size_t)rowB * D + g * 8;

    s16x8 a[16], b[16];
#pragma unroll
    for (int kk = 0; kk < 16; ++kk) {
        a[kk] = *(const s16x8*)(pA + kk * 32);
        b[kk] = *(const s16x8*)(pB + kk * 32);
    }
    f32x4 acc = (f32x4){0.f, 0.f, 0.f, 0.f};
#pragma unroll
    for (int kk = 0; kk < 16; ++kk)
        acc = __builtin_amdgcn_mfma_f32_16x16x32_bf16(a[kk], b[kk], acc, 0, 0, 0);

    float lsum = 0.f;
#pragma unroll
    for (int j = 0; j < 4; ++j) {
        const int p = g * 4 + j;                 // output row (query p)
        const float logit = acc[j] * 10.f;
        const bool isneg = (cc >= KPOS) && (cc < 15);
        const bool ispos = (cc == p);
        float x = (ispos || isneg) ? logit : -__builtin_inff();
        float m = x;
#pragma unroll
        for (int off = 1; off < 16; off <<= 1) m = fmaxf(m, __shfl_xor(m, off));
        float e = (ispos || isneg) ? expf(logit - m) : 0.f;
        float sx = e;
#pragma unroll
        for (int off = 1; off < 16; off <<= 1) sx += __shfl_xor(sx, off);
        float l0 = ispos ? logit : 0.f;
#pragma unroll
        for (int off = 1; off < 16; off <<= 1) l0 += __shfl_xor(l0, off);
        if (p < KPOS && ispos) lsum += logf(sx) + m - l0;   // one lane per row
    }

#pragma unroll
    for (int off = 32; off > 0; off >>= 1) lsum += __shfl_xor(lsum, off);
    if (lane == 0) wsum[wave] = lsum;
    __syncthreads();
    if (threadIdx.x == 0)
        partials[blockIdx.x] = wsum[0] + wsum[1] + wsum[2] + wsum[3];
}

// ---------------------------------------------------------------------------
// Kernel 4: final deterministic reduce of 1024 block partials.
// ---------------------------------------------------------------------------
__global__ __launch_bounds__(256) void reduce_kernel(const float* __restrict__ partials,
                                                     float* __restrict__ out) {
    __shared__ float wsum[4];
    const int wave = threadIdx.x >> 6, lane = threadIdx.x & 63;
    float s = partials[threadIdx.x] + partials[threadIdx.x + 256] +
              partials[threadIdx.x + 512] + partials[threadIdx.x + 768];
#pragma unroll
    for (int off = 32; off > 0; off >>= 1) s += __shfl_xor(s, off);
    if (lane == 0) wsum[wave] = s;
    __syncthreads();
    if (threadIdx.x == 0)
        *out = (wsum[0] + wsum[1] + wsum[2] + wsum[3]) * (1.0f / (float)(N * KPOS));
}

// ---------------------------------------------------------------------------
extern "C" void kernel_launch(void* const* d_in, const int* in_sizes, int n_in,
                              void* d_out, int out_size, void* d_ws, size_t ws_size,
                              hipStream_t stream) {
    const float* anchor = (const float*)d_in[0];
    const float* sample = (const float*)d_in[1];
    float* out = (float*)d_out;

    char* ws = (char*)d_ws;
    unsigned short* Abf    = (unsigned short*)ws;                               // 4 MiB
    unsigned short* s_norm = (unsigned short*)(ws + (size_t)4 * 1024 * 1024);   // 4 MiB
    unsigned short* sim    = (unsigned short*)(ws + (size_t)8 * 1024 * 1024);   // 32 MiB
    float* partials = (float*)(ws + (size_t)40 * 1024 * 1024);                  // 4 KiB

    norm_kernel<<<2048, 256, 0, stream>>>(anchor, sample, Abf, s_norm);

    gemm_bf16<<<NJOB, 256, 0, stream>>>(Abf, sim);

    fused_topk_loss<<<N / 4, 256, 0, stream>>>(sim, s_norm, partials);

    reduce_kernel<<<1, 256, 0, stream>>>(partials, out);
}